// Round 4
// baseline (399.868 us; speedup 1.0000x reference)
//
#include <hip/hip_runtime.h>
#include <hip/hip_bf16.h>

// Problem constants (S=2048, B=2, E=2048, H=32, D=64)
#define S_LEN 2048
#define BATCH 2
#define EMB   2048
#define NH    32
#define HD    64
#define M_ROWS (S_LEN * BATCH)   // 4096
#define QKV_N  (3 * EMB)         // 6144

typedef short bf16x8 __attribute__((ext_vector_type(8)));
typedef float f32x4  __attribute__((ext_vector_type(4)));

__device__ __forceinline__ unsigned short f2bf(float f) {
  unsigned int u = __float_as_uint(f);
  u += 0x7fffu + ((u >> 16) & 1u);       // round-to-nearest-even
  return (unsigned short)(u >> 16);
}
__device__ __forceinline__ float bf2f(unsigned short h) {
  return __uint_as_float(((unsigned int)h) << 16);
}
__device__ __forceinline__ void async_copy16(const void* g, void* lds_d) {
  __builtin_amdgcn_global_load_lds(
      (const __attribute__((address_space(1))) void*)g,
      (__attribute__((address_space(3))) void*)lds_d, 16, 0, 0);
}

#if __has_builtin(__builtin_amdgcn_exp2f)
#define EXP2F(x) __builtin_amdgcn_exp2f(x)
#else
#define EXP2F(x) __expf((x) * 0.6931471805599453f)
#endif

// ---------------- prep kernels ----------------

__global__ __launch_bounds__(256) void cast_to_bf16(
    const float* __restrict__ in, unsigned short* __restrict__ out, int n4) {
  int i = blockIdx.x * 256 + threadIdx.x;
  if (i >= n4) return;
  float4 v = reinterpret_cast<const float4*>(in)[i];
  ushort4 o;
  o.x = f2bf(v.x); o.y = f2bf(v.y); o.z = f2bf(v.z); o.w = f2bf(v.w);
  reinterpret_cast<ushort4*>(out)[i] = o;
}

// in [R][C] f32 -> out [C][R] bf16.  64x64 tile, both sides coalesced
// (256 B/wave reads, 128 B/wave writes); same proven pattern as transpose_v.
__global__ __launch_bounds__(256) void transpose_cast(
    const float* __restrict__ in, unsigned short* __restrict__ out, int R, int C) {
  __shared__ unsigned short t[64][65];
  const int bc = blockIdx.x * 64, br = blockIdx.y * 64;
  const int tx = threadIdx.x & 63, ty = threadIdx.x >> 6;   // ty 0..3
  #pragma unroll
  for (int rr = ty; rr < 64; rr += 4)
    t[rr][tx] = f2bf(in[(size_t)(br + rr) * C + bc + tx]);
  __syncthreads();
  #pragma unroll
  for (int rr = ty; rr < 64; rr += 4)
    out[(size_t)(bc + rr) * R + br + tx] = t[tx][rr];
}

// ---------------- QKV GEMM (R1-measured-best): 256x128 tile, BK=64, 8 waves,
// triple-buffered LDS, 2 phases/K-tile with counted vmcnt + setprio.
// Buffer rotation: tile t computes from buf[t%3]; stages during tile t target
// buf[(t+2)%3], whose last readers finished before the preceding boundary
// barrier. vmcnt(6) at boundaries leaves tile t+2's 6 loads in flight; never
// drained to 0 mid-loop. LDS XOR swizzle: phys chunk p holds global chunk
// p^(row&7); fragment reads address chunk (ks*4+lq)^(R&7) -> 2-way only.

constexpr int TILE_SH = 24576;                 // shorts/buffer: A 256x64 + B 128x64
constexpr int GEMM_LDS_BYTES = 3 * TILE_SH * 2; // 147456 B

__global__ __launch_bounds__(512, 2) void gemm_qkv(
    const unsigned short* __restrict__ A,
    const unsigned short* __restrict__ Wt,
    const float* __restrict__ bias,
    unsigned short* __restrict__ Qo,
    unsigned short* __restrict__ Ko,
    unsigned short* __restrict__ Vo) {
  extern __shared__ unsigned short lds[];
  const int tid = threadIdx.x;               // 0..511
  const int n0 = blockIdx.x * 128;
  const int m0 = blockIdx.y * 256;
  const int wave = tid >> 6, lane = tid & 63;
  const int wm = (wave >> 1) * 64, wn = (wave & 1) * 64;   // 4M x 2N waves
  const int lm = lane & 15, lq = lane >> 4;
  const int K = 2048;
  const int NT = K / 64;                     // 32 K-tiles

  const int srow = tid >> 3;                 // 0..63
  const int gch  = (tid & 7) ^ (srow & 7);
  const unsigned short* Ab = A  + (size_t)(m0 + srow) * K + gch * 8;
  const unsigned short* Bb = Wt + (size_t)(n0 + srow) * K + gch * 8;

  auto stA = [&](int bufi, int k0, int rep) {
    async_copy16(Ab + (size_t)rep * 64 * K + k0,
                 lds + (size_t)bufi * TILE_SH + ((size_t)rep * 512 + tid) * 8);
  };
  auto stB = [&](int bufi, int k0, int rep) {
    async_copy16(Bb + (size_t)rep * 64 * K + k0,
                 lds + (size_t)bufi * TILE_SH + 16384 + ((size_t)rep * 512 + tid) * 8);
  };

  f32x4 acc[4][4] = {};

  // prologue: stage tiles 0 and 1; wait for tile 0 only (tile 1 stays in flight)
  stA(0, 0, 0); stA(0, 0, 1); stA(0, 0, 2); stA(0, 0, 3); stB(0, 0, 0); stB(0, 0, 1);
  stA(1, 64, 0); stA(1, 64, 1); stA(1, 64, 2); stA(1, 64, 3); stB(1, 64, 0); stB(1, 64, 1);
  asm volatile("s_waitcnt vmcnt(6)" ::: "memory");
  __builtin_amdgcn_s_barrier();

  int cur = 0;
  for (int t = 0; t < NT; t++) {
    const unsigned short* Abuf = lds + (size_t)cur * TILE_SH;
    const unsigned short* Bbuf = Abuf + 16384;
    const int pb = (cur >= 1) ? cur - 1 : 2;   // (cur+2)%3
    const int pk = (t + 2) * 64;
    const bool pre = (t + 2) < NT;

    // ---- phase 0: read all B frags + A rows i=0,1; stage 3 of tile t+2 ----
    bf16x8 b[4][2], a[2][2];
    #pragma unroll
    for (int j = 0; j < 4; j++) {
      const int R = wn + j * 16 + lm;
      #pragma unroll
      for (int ks = 0; ks < 2; ks++)
        b[j][ks] = *reinterpret_cast<const bf16x8*>(
            Bbuf + (size_t)R * 64 + (((ks * 4 + lq) ^ (R & 7)) * 8));
    }
    #pragma unroll
    for (int i = 0; i < 2; i++) {
      const int R = wm + i * 16 + lm;
      #pragma unroll
      for (int ks = 0; ks < 2; ks++)
        a[i][ks] = *reinterpret_cast<const bf16x8*>(
            Abuf + (size_t)R * 64 + (((ks * 4 + lq) ^ (R & 7)) * 8));
    }
    if (pre) { stA(pb, pk, 0); stA(pb, pk, 1); stB(pb, pk, 0); }
    __builtin_amdgcn_s_barrier();
    asm volatile("s_waitcnt lgkmcnt(0)" ::: "memory");
    __builtin_amdgcn_s_setprio(1);
    #pragma unroll
    for (int ks = 0; ks < 2; ks++)
      #pragma unroll
      for (int i = 0; i < 2; i++)
        #pragma unroll
        for (int j = 0; j < 4; j++)
          acc[i][j] = __builtin_amdgcn_mfma_f32_16x16x32_bf16(a[i][ks], b[j][ks], acc[i][j], 0, 0, 0);
    __builtin_amdgcn_s_setprio(0);
    __builtin_amdgcn_s_barrier();

    // ---- phase 1: read A rows i=2,3; stage remaining 3 of tile t+2 ----
    #pragma unroll
    for (int i = 0; i < 2; i++) {
      const int R = wm + (i + 2) * 16 + lm;
      #pragma unroll
      for (int ks = 0; ks < 2; ks++)
        a[i][ks] = *reinterpret_cast<const bf16x8*>(
            Abuf + (size_t)R * 64 + (((ks * 4 + lq) ^ (R & 7)) * 8));
    }
    if (pre) { stA(pb, pk, 2); stA(pb, pk, 3); stB(pb, pk, 1); }
    __builtin_amdgcn_s_barrier();
    asm volatile("s_waitcnt lgkmcnt(0)" ::: "memory");
    __builtin_amdgcn_s_setprio(1);
    #pragma unroll
    for (int ks = 0; ks < 2; ks++)
      #pragma unroll
      for (int i = 0; i < 2; i++)
        #pragma unroll
        for (int j = 0; j < 4; j++)
          acc[i + 2][j] = __builtin_amdgcn_mfma_f32_16x16x32_bf16(a[i][ks], b[j][ks], acc[i + 2][j], 0, 0, 0);
    __builtin_amdgcn_s_setprio(0);
    if (t + 1 < NT) {
      if (pre) asm volatile("s_waitcnt vmcnt(6)" ::: "memory");  // tile t+1 landed
      else     asm volatile("s_waitcnt vmcnt(0)" ::: "memory");  // final drain
      __builtin_amdgcn_s_barrier();
    }
    cur = (cur == 2) ? 0 : cur + 1;
  }

  // epilogue: bias (+RoPE for Q/K) + bf16 + scatter into [B,H,S,D]
  const int which = n0 >> 11;   // 0=q 1=k 2=v, uniform per block
  unsigned short* dst = (which == 0) ? Qo : (which == 1) ? Ko : Vo;
  float bv[4];
  #pragma unroll
  for (int j = 0; j < 4; j++) bv[j] = bias[n0 + wn + j * 16 + lm];

  if (which < 2) {
    // RoPE pairs (d, d+32) = (acc[i][j], acc[i][j+2]) for j=0,1 (d = j*16+lm)
    #pragma unroll
    for (int j = 0; j < 2; j++) {
      const int n = n0 + wn + j * 16 + lm;
      const int e = n & (EMB - 1), h = e >> 6, d = e & 63;   // d < 32
      const float invf = EXP2F((float)d * -0.4152410118609203f);  // 10000^(-d/32)
      #pragma unroll
      for (int i = 0; i < 4; i++) {
        #pragma unroll
        for (int r = 0; r < 4; r++) {
          const int m = m0 + wm + i * 16 + lq * 4 + r;
          const int s = m >> 1, b = m & 1;
          const float v1 = acc[i][j][r]     + bv[j];
          const float v2 = acc[i][j + 2][r] + bv[j + 2];
          float sn, cs;
          __sincosf((float)s * invf, &sn, &cs);
          const size_t base = (((size_t)b * NH + h) * S_LEN + s) * HD + d;
          dst[base]      = f2bf(v1 * cs - v2 * sn);
          dst[base + 32] = f2bf(v2 * cs + v1 * sn);
        }
      }
    }
  } else {
    #pragma unroll
    for (int j = 0; j < 4; j++) {
      const int n = n0 + wn + j * 16 + lm;
      const int e = n & (EMB - 1), h = e >> 6, d = e & 63;
      #pragma unroll
      for (int i = 0; i < 4; i++) {
        #pragma unroll
        for (int r = 0; r < 4; r++) {
          const int m = m0 + wm + i * 16 + lq * 4 + r;
          const int s = m >> 1, b = m & 1;
          dst[(((size_t)b * NH + h) * S_LEN + s) * HD + d] = f2bf(acc[i][j][r] + bv[j]);
        }
      }
    }
  }
}

// ---------------- V [B,H,S,D] -> VT [B,H,D,S] ----------------

__global__ __launch_bounds__(256) void transpose_v(
    const unsigned short* __restrict__ V, unsigned short* __restrict__ VT) {
  __shared__ unsigned short t[64][65];
  const int bh = blockIdx.y;
  const int s0 = blockIdx.x * 64;
  const int tx = threadIdx.x & 63, ty = threadIdx.x >> 6;  // ty 0..3
  const unsigned short* src = V + ((size_t)bh * S_LEN + s0) * HD;
  #pragma unroll
  for (int r = ty; r < 64; r += 4)
    t[r][tx] = src[(size_t)r * HD + tx];
  __syncthreads();
  unsigned short* dst = VT + (size_t)bh * HD * S_LEN + s0;
  #pragma unroll
  for (int r = ty; r < 64; r += 4)
    dst[(size_t)r * S_LEN + tx] = t[tx][r];
}

// ---------------- Flash attention (causal), bf16 MFMA, fixed-max softmax ----------------
// ROUND-4 CHANGE: V is NO LONGER staged in LDS. Per-bh K/V is 256 KB ->
// L2-resident; V-staging through LDS was pure overhead (Common-mistake #7 /
// m169: dropping V-staging at L2-fit sizes was +26%). vf fragments are read
// directly from VT (16 B/lane over 16 rows, L2-friendly). LDS 50 -> 34 KB
// (more blocks/CU -> more TLP to hide the V L2-hit latency).

__global__ __launch_bounds__(256) void attn_kernel(
    const unsigned short* __restrict__ Q,
    const unsigned short* __restrict__ K,
    const unsigned short* __restrict__ VT,
    unsigned short* __restrict__ ctx) {
  const int bh = blockIdx.x;               // b*32+h
  const int p  = blockIdx.y;               // 0..7 strip pair
  const int tid = threadIdx.x;
  const int wave = tid >> 6, lane = tid & 63;
  const int lm = lane & 15, lq = lane >> 4;
  const int b = bh >> 5, h = bh & 31;
  const char* Qb8 = (const char*)(Q  + (size_t)bh * S_LEN * HD);
  const char* Kb8 = (const char*)(K  + (size_t)bh * S_LEN * HD);
  const char* Vb8 = (const char*)(VT + (size_t)bh * HD * S_LEN);

  __shared__ __align__(16) unsigned short Ks[2][2][64][32];  // [buf][half][row][32]
  __shared__ __align__(16) unsigned short Pbuf[4][32][72];
  unsigned short* Pw = &Pbuf[wave][0][0];

  const float C = 0.18033688011112042f;    // (1/8) * log2(e)
  const int q0A = p * 128, q0B = (15 - p) * 128;
  const int r0A = q0A + wave * 32, r0B = q0B + wave * 32;
  const int nt = (q0B >> 6) + 2;           // heavy strip's tile count

  const int srw = tid >> 2, sc16 = (tid & 3) * 16;

  bf16x8 qf[2][2][2];                      // [strip][i][ks]
  #pragma unroll
  for (int s = 0; s < 2; s++) {
    const int rr = (s == 0) ? r0A : r0B;
    #pragma unroll
    for (int i = 0; i < 2; i++)
      #pragma unroll
      for (int ks = 0; ks < 2; ks++)
        qf[s][i][ks] = *reinterpret_cast<const bf16x8*>(
            Qb8 + (size_t)(rr + i*16 + lm) * 128 + ks*64 + lq*16);
  }

  f32x4 O[2][2][4] = {};
  float l[2][2][4] = {};

  {
    char* kd = (char*)&Ks[0][0][0][0];
    async_copy16(Kb8 + (size_t)srw * 128      + sc16, kd        + tid*16);
    async_copy16(Kb8 + (size_t)srw * 128 + 64 + sc16, kd + 4096 + tid*16);
  }
  __syncthreads();

  for (int t = 0; t < nt; t++) {
    const int t0 = t * 64;
    const int buf = t & 1;

    if (t + 1 < nt) {
      const int t1 = t0 + 64;
      char* kd = (char*)&Ks[buf ^ 1][0][0][0];
      async_copy16(Kb8 + (size_t)(t1 + srw) * 128      + sc16, kd        + tid*16);
      async_copy16(Kb8 + (size_t)(t1 + srw) * 128 + 64 + sc16, kd + 4096 + tid*16);
    }

    const char* KsB = (const char*)&Ks[buf][0][0][0];

    #pragma unroll
    for (int s = 0; s < 2; s++) {
      const int rr = (s == 0) ? r0A : r0B;
      if (t0 <= rr + 31) {
        const bool clean = (t0 + 63 <= rr);
        const int jmax  = clean ? 4 : ((rr == t0) ? 2 : 4);
        const int kslim = clean ? 2 : ((rr == t0) ? 1 : 2);
        const int srow_c = rr + lq * 4;

        f32x4 sc[2][4] = {};
        #pragma unroll
        for (int ks = 0; ks < 2; ks++) {
          bf16x8 kf[4];
          #pragma unroll
          for (int j = 0; j < 4; j++)
            if (j < jmax)
              kf[j] = *reinterpret_cast<const bf16x8*>(
                  KsB + ks*4096 + (j*16 + lm)*64 + lq*16);
          #pragma unroll
          for (int i = 0; i < 2; i++)
            #pragma unroll
            for (int j = 0; j < 4; j++)
              if (j < jmax)
                sc[i][j] = __builtin_amdgcn_mfma_f32_16x16x32_bf16(
                    qf[s][i][ks], kf[j], sc[i][j], 0, 0, 0);
        }

        if (clean) {
          #pragma unroll
          for (int i = 0; i < 2; i++)
            #pragma unroll
            for (int j = 0; j < 4; j++)
              #pragma unroll
              for (int r = 0; r < 4; r++) {
                const float pe = EXP2F(sc[i][j][r] * C);
                l[s][i][r] += pe;
                Pw[(i*16 + lq*4 + r) * 72 + j*16 + lm] = f2bf(pe);
              }
        } else {
          #pragma unroll
          for (int i = 0; i < 2; i++)
            #pragma unroll
            for (int j = 0; j < 4; j++)
              if (j < jmax)
                #pragma unroll
                for (int r = 0; r < 4; r++) {
                  const int srow = srow_c + i*16 + r;
                  const int tcol = t0 + j*16 + lm;
                  const float pe = (tcol <= srow) ? EXP2F(sc[i][j][r] * C) : 0.0f;
                  l[s][i][r] += pe;
                  Pw[(i*16 + lq*4 + r) * 72 + j*16 + lm] = f2bf(pe);
                }
        }

        // O += P V   (V fragments straight from global VT, L2-resident)
        #pragma unroll
        for (int ks = 0; ks < 2; ks++) {
          if (ks < kslim) {
            bf16x8 pf[2], vf[4];
            #pragma unroll
            for (int i = 0; i < 2; i++)
              pf[i] = *reinterpret_cast<const bf16x8*>(Pw + (i*16 + lm)*72 + ks*32 + lq*8);
            #pragma unroll
            for (int j = 0; j < 4; j++)
              vf[j] = *reinterpret_cast<const bf16x8*>(
                  Vb8 + (size_t)(j*16 + lm) * 4096 + t0*2 + ks*64 + lq*16);
            #pragma unroll
            for (int i = 0; i < 2; i++)
              #pragma unroll
              for (int j = 0; j < 4; j++)
                O[s][i][j] = __builtin_amdgcn_mfma_f32_16x16x32_bf16(
                    pf[i], vf[j], O[s][i][j], 0, 0, 0);
          }
        }
      }
    }
    __syncthreads();
  }

  #pragma unroll
  for (int s = 0; s < 2; s++) {
    const int rr = (s == 0) ? r0A : r0B;
    #pragma unroll
    for (int i = 0; i < 2; i++) {
      #pragma unroll
      for (int r = 0; r < 4; r++) {
        float sum = l[s][i][r];
        sum += __shfl_xor(sum, 1, 64);
        sum += __shfl_xor(sum, 2, 64);
        sum += __shfl_xor(sum, 4, 64);
        sum += __shfl_xor(sum, 8, 64);
        const float inv = 1.0f / sum;
        const int srow = rr + lq*4 + i*16 + r;
        #pragma unroll
        for (int j = 0; j < 4; j++) {
          const int d = j*16 + lm;
          ctx[((size_t)srow * BATCH + b) * EMB + h*HD + d] = f2bf(O[s][i][j][r] * inv);
        }
      }
    }
  }
}

// ---------------- Output GEMM: same R1 256x128 schedule, f32 + bias epilogue ----------------

__global__ __launch_bounds__(512, 2) void gemm_out(
    const unsigned short* __restrict__ A,
    const unsigned short* __restrict__ Wt,
    const float* __restrict__ bias,
    float* __restrict__ out) {
  extern __shared__ unsigned short lds[];
  const int tid = threadIdx.x;
  const int n0 = blockIdx.x * 128;
  const int m0 = blockIdx.y * 256;
  const int wave = tid >> 6, lane = tid & 63;
  const int wm = (wave >> 1) * 64, wn = (wave & 1) * 64;
  const int lm = lane & 15, lq = lane >> 4;
  const int K = 2048;
  const int NT = K / 64;

  const int srow = tid >> 3;
  const int gch  = (tid & 7) ^ (srow & 7);
  const unsigned short* Ab = A  + (size_t)(m0 + srow) * K + gch * 8;
  const unsigned short* Bb = Wt + (size_t)(n0 + srow) * K + gch * 8;

  auto stA = [&](int bufi, int k0, int rep) {
    async_copy16(Ab + (size_t)rep * 64 * K + k0,
                 lds + (size_t)bufi * TILE_SH + ((size_t)rep * 512 + tid) * 8);
  };
  auto stB = [&](int bufi, int k0, int rep) {
    async_copy16(Bb + (size_t)rep * 64 * K + k0,
                 lds + (size_t)bufi * TILE_SH + 16384 + ((size_t)rep * 512 + tid) * 8);
  };

  f32x4 acc[4][4] = {};

  stA(0, 0, 0); stA(0, 0, 1); stA(0, 0, 2); stA(0, 0, 3); stB(0, 0, 0); stB(0, 0, 1);
  stA(1, 64, 0); stA(1, 64, 1); stA(1, 64, 2); stA(1, 64, 3); stB(1, 64, 0); stB(1, 64, 1);
  asm volatile("s_waitcnt vmcnt(6)" ::: "memory");
  __builtin_amdgcn_s_barrier();

  int cur = 0;
  for (int t = 0; t < NT; t++) {
    const unsigned short* Abuf = lds + (size_t)cur * TILE_SH;
    const unsigned short* Bbuf = Abuf + 16384;
    const int pb = (cur >= 1) ? cur - 1 : 2;
    const int pk = (t + 2) * 64;
    const bool pre = (t + 2) < NT;

    bf16x8 b[4][2], a[2][2];
    #pragma unroll
    for (int j = 0; j < 4; j++) {
      const int R = wn + j * 16 + lm;
      #pragma unroll
      for (int ks = 0; ks < 2; ks++)
        b[j][ks] = *reinterpret_cast<const bf16x8*>(
            Bbuf + (size_t)R * 64 + (((ks * 4 + lq) ^ (R & 7)) * 8));
    }
    #pragma unroll
    for (int i = 0; i < 2; i++) {
      const int R = wm + i * 16 + lm;
      #pragma unroll
      for (int ks = 0; ks < 2; ks++)
        a[i][ks] = *reinterpret_cast<const bf16x8*>(
            Abuf + (size_t)R * 64 + (((ks * 4 + lq) ^ (R & 7)) * 8));
    }
    if (pre) { stA(pb, pk, 0); stA(pb, pk, 1); stB(pb, pk, 0); }
    __builtin_amdgcn_s_barrier();
    asm volatile("s_waitcnt lgkmcnt(0)" ::: "memory");
    __builtin_amdgcn_s_setprio(1);
    #pragma unroll
    for (int ks = 0; ks < 2; ks++)
      #pragma unroll
      for (int i = 0; i < 2; i++)
        #pragma unroll
        for (int j = 0; j < 4; j++)
          acc[i][j] = __builtin_amdgcn_mfma_f32_16x16x32_bf16(a[i][ks], b[j][ks], acc[i][j], 0, 0, 0);
    __builtin_amdgcn_s_setprio(0);
    __builtin_amdgcn_s_barrier();

    #pragma unroll
    for (int i = 0; i < 2; i++) {
      const int R = wm + (i + 2) * 16 + lm;
      #pragma unroll
      for (int ks = 0; ks < 2; ks++)
        a[i][ks] = *reinterpret_cast<const bf16x8*>(
            Abuf + (size_t)R * 64 + (((ks * 4 + lq) ^ (R & 7)) * 8));
    }
    if (pre) { stA(pb, pk, 2); stA(pb, pk, 3); stB(pb, pk, 1); }
    __builtin_amdgcn_s_barrier();
    asm volatile("s_waitcnt lgkmcnt(0)" ::: "memory");
    __builtin_amdgcn_s_setprio(1);
    #pragma unroll
    for (int ks = 0; ks < 2; ks++)
      #pragma unroll
      for (int i = 0; i < 2; i++)
        #pragma unroll
        for (int j = 0; j < 4; j++)
          acc[i + 2][j] = __builtin_amdgcn_mfma_f32_16x16x32_bf16(a[i][ks], b[j][ks], acc[i + 2][j], 0, 0, 0);
    __builtin_amdgcn_s_setprio(0);
    if (t + 1 < NT) {
      if (pre) asm volatile("s_waitcnt vmcnt(6)" ::: "memory");
      else     asm volatile("s_waitcnt vmcnt(0)" ::: "memory");
      __builtin_amdgcn_s_barrier();
    }
    cur = (cur == 2) ? 0 : cur + 1;
  }

  #pragma unroll
  for (int j = 0; j < 4; j++) {
    const int n = n0 + wn + j * 16 + lm;
    const float bv = bias[n];
    #pragma unroll
    for (int i = 0; i < 4; i++) {
      #pragma unroll
      for (int r = 0; r < 4; r++) {
        const int m = m0 + wm + i * 16 + lq * 4 + r;
        out[(size_t)m * EMB + n] = acc[i][j][r] + bv;
      }
    }
  }
}

// ---------------- host launcher ----------------

extern "C" void kernel_launch(void* const* d_in, const int* in_sizes, int n_in,
                              void* d_out, int out_size, void* d_ws, size_t ws_size,
                              hipStream_t stream) {
  const float* hidden = (const float*)d_in[0];
  const float* qkv_w  = (const float*)d_in[1];
  const float* qkv_b  = (const float*)d_in[2];
  const float* out_w  = (const float*)d_in[3];
  const float* out_b  = (const float*)d_in[4];
  float* out = (float*)d_out;

  static bool attr_set = false;
  if (!attr_set) {
    hipFuncSetAttribute(reinterpret_cast<const void*>(gemm_qkv),
                        hipFuncAttributeMaxDynamicSharedMemorySize, GEMM_LDS_BYTES);
    hipFuncSetAttribute(reinterpret_cast<const void*>(gemm_out),
                        hipFuncAttributeMaxDynamicSharedMemorySize, GEMM_LDS_BYTES);
    attr_set = true;
  }

  unsigned short* ws = (unsigned short*)d_ws;
  unsigned short* hbf   = ws;                                  // 4096*2048
  unsigned short* qkvwT = hbf   + (size_t)M_ROWS * EMB;        // 6144*2048
  unsigned short* outwT = qkvwT + (size_t)QKV_N * EMB;         // 2048*2048
  unsigned short* Qb    = outwT + (size_t)EMB * EMB;           // 64*2048*64 each
  unsigned short* Kb    = Qb    + (size_t)64 * S_LEN * HD;
  unsigned short* Vb    = Kb    + (size_t)64 * S_LEN * HD;
  unsigned short* VTb   = Vb    + (size_t)64 * S_LEN * HD;
  unsigned short* ctx   = VTb   + (size_t)64 * S_LEN * HD;     // 4096*2048

  // 1. casts / transposes (64x64 coalesced transpose_cast)
  cast_to_bf16<<<(M_ROWS * EMB / 4) / 256, 256, 0, stream>>>(hidden, hbf, M_ROWS * EMB / 4);
  transpose_cast<<<dim3(QKV_N / 64, EMB / 64), 256, 0, stream>>>(qkv_w, qkvwT, EMB, QKV_N);
  transpose_cast<<<dim3(EMB / 64, EMB / 64), 256, 0, stream>>>(out_w, outwT, EMB, EMB);

  // 2. fused QKV projection + bias + RoPE + scatter (R1-best 256x128 schedule)
  gemm_qkv<<<dim3(QKV_N / 128, M_ROWS / 256), 512, GEMM_LDS_BYTES, stream>>>(
      hbf, qkvwT, qkv_b, Qb, Kb, Vb);

  // 3. V transpose
  transpose_v<<<dim3(S_LEN / 64, 64), 256, 0, stream>>>(Vb, VTb);

  // 4. causal flash attention (V read direct from L2-resident VT; no V staging)
  attn_kernel<<<dim3(64, 8), 256, 0, stream>>>(Qb, Kb, VTb, ctx);

  // 5. output projection (R1 256x128 schedule)
  gemm_out<<<dim3(EMB / 128, M_ROWS / 256), 512, GEMM_LDS_BYTES, stream>>>(
      ctx, outwT, out_b, out);
}

// Round 5
// 390.824 us; speedup vs baseline: 1.0231x; 1.0231x over previous
//
#include <hip/hip_runtime.h>
#include <hip/hip_bf16.h>

// Problem constants (S=2048, B=2, E=2048, H=32, D=64)
#define S_LEN 2048
#define BATCH 2
#define EMB   2048
#define NH    32
#define HD    64
#define M_ROWS (S_LEN * BATCH)   // 4096
#define QKV_N  (3 * EMB)         // 6144

typedef short bf16x8 __attribute__((ext_vector_type(8)));
typedef float f32x4  __attribute__((ext_vector_type(4)));

__device__ __forceinline__ unsigned short f2bf(float f) {
  unsigned int u = __float_as_uint(f);
  u += 0x7fffu + ((u >> 16) & 1u);       // round-to-nearest-even
  return (unsigned short)(u >> 16);
}
__device__ __forceinline__ float bf2f(unsigned short h) {
  return __uint_as_float(((unsigned int)h) << 16);
}
__device__ __forceinline__ void async_copy16(const void* g, void* lds_d) {
  __builtin_amdgcn_global_load_lds(
      (const __attribute__((address_space(1))) void*)g,
      (__attribute__((address_space(3))) void*)lds_d, 16, 0, 0);
}

#if __has_builtin(__builtin_amdgcn_exp2f)
#define EXP2F(x) __builtin_amdgcn_exp2f(x)
#else
#define EXP2F(x) __expf((x) * 0.6931471805599453f)
#endif

// ---------------- prep kernels ----------------

__global__ __launch_bounds__(256) void cast_to_bf16(
    const float* __restrict__ in, unsigned short* __restrict__ out, int n4) {
  int i = blockIdx.x * 256 + threadIdx.x;
  if (i >= n4) return;
  float4 v = reinterpret_cast<const float4*>(in)[i];
  ushort4 o;
  o.x = f2bf(v.x); o.y = f2bf(v.y); o.z = f2bf(v.z); o.w = f2bf(v.w);
  reinterpret_cast<ushort4*>(out)[i] = o;
}

// in [R][C] f32 -> out [C][R] bf16.  64x64 tile, both sides coalesced.
__global__ __launch_bounds__(256) void transpose_cast(
    const float* __restrict__ in, unsigned short* __restrict__ out, int R, int C) {
  __shared__ unsigned short t[64][65];
  const int bc = blockIdx.x * 64, br = blockIdx.y * 64;
  const int tx = threadIdx.x & 63, ty = threadIdx.x >> 6;   // ty 0..3
  #pragma unroll
  for (int rr = ty; rr < 64; rr += 4)
    t[rr][tx] = f2bf(in[(size_t)(br + rr) * C + bc + tx]);
  __syncthreads();
  #pragma unroll
  for (int rr = ty; rr < 64; rr += 4)
    out[(size_t)(bc + rr) * R + br + tx] = t[tx][rr];
}

// ---------------- QKV GEMM (R1-measured-best): 256x128 tile, BK=64, 8 waves,
// triple-buffered LDS, 2 phases/K-tile with counted vmcnt + setprio.

constexpr int TILE_SH = 24576;                 // shorts/buffer: A 256x64 + B 128x64
constexpr int GEMM_LDS_BYTES = 3 * TILE_SH * 2; // 147456 B

__global__ __launch_bounds__(512, 2) void gemm_qkv(
    const unsigned short* __restrict__ A,
    const unsigned short* __restrict__ Wt,
    const float* __restrict__ bias,
    unsigned short* __restrict__ Qo,
    unsigned short* __restrict__ Ko,
    unsigned short* __restrict__ Vo) {
  extern __shared__ unsigned short lds[];
  const int tid = threadIdx.x;               // 0..511
  const int n0 = blockIdx.x * 128;
  const int m0 = blockIdx.y * 256;
  const int wave = tid >> 6, lane = tid & 63;
  const int wm = (wave >> 1) * 64, wn = (wave & 1) * 64;   // 4M x 2N waves
  const int lm = lane & 15, lq = lane >> 4;
  const int K = 2048;
  const int NT = K / 64;                     // 32 K-tiles

  const int srow = tid >> 3;                 // 0..63
  const int gch  = (tid & 7) ^ (srow & 7);
  const unsigned short* Ab = A  + (size_t)(m0 + srow) * K + gch * 8;
  const unsigned short* Bb = Wt + (size_t)(n0 + srow) * K + gch * 8;

  auto stA = [&](int bufi, int k0, int rep) {
    async_copy16(Ab + (size_t)rep * 64 * K + k0,
                 lds + (size_t)bufi * TILE_SH + ((size_t)rep * 512 + tid) * 8);
  };
  auto stB = [&](int bufi, int k0, int rep) {
    async_copy16(Bb + (size_t)rep * 64 * K + k0,
                 lds + (size_t)bufi * TILE_SH + 16384 + ((size_t)rep * 512 + tid) * 8);
  };

  f32x4 acc[4][4] = {};

  stA(0, 0, 0); stA(0, 0, 1); stA(0, 0, 2); stA(0, 0, 3); stB(0, 0, 0); stB(0, 0, 1);
  stA(1, 64, 0); stA(1, 64, 1); stA(1, 64, 2); stA(1, 64, 3); stB(1, 64, 0); stB(1, 64, 1);
  asm volatile("s_waitcnt vmcnt(6)" ::: "memory");
  __builtin_amdgcn_s_barrier();

  int cur = 0;
  for (int t = 0; t < NT; t++) {
    const unsigned short* Abuf = lds + (size_t)cur * TILE_SH;
    const unsigned short* Bbuf = Abuf + 16384;
    const int pb = (cur >= 1) ? cur - 1 : 2;   // (cur+2)%3
    const int pk = (t + 2) * 64;
    const bool pre = (t + 2) < NT;

    bf16x8 b[4][2], a[2][2];
    #pragma unroll
    for (int j = 0; j < 4; j++) {
      const int R = wn + j * 16 + lm;
      #pragma unroll
      for (int ks = 0; ks < 2; ks++)
        b[j][ks] = *reinterpret_cast<const bf16x8*>(
            Bbuf + (size_t)R * 64 + (((ks * 4 + lq) ^ (R & 7)) * 8));
    }
    #pragma unroll
    for (int i = 0; i < 2; i++) {
      const int R = wm + i * 16 + lm;
      #pragma unroll
      for (int ks = 0; ks < 2; ks++)
        a[i][ks] = *reinterpret_cast<const bf16x8*>(
            Abuf + (size_t)R * 64 + (((ks * 4 + lq) ^ (R & 7)) * 8));
    }
    if (pre) { stA(pb, pk, 0); stA(pb, pk, 1); stB(pb, pk, 0); }
    __builtin_amdgcn_s_barrier();
    asm volatile("s_waitcnt lgkmcnt(0)" ::: "memory");
    __builtin_amdgcn_s_setprio(1);
    #pragma unroll
    for (int ks = 0; ks < 2; ks++)
      #pragma unroll
      for (int i = 0; i < 2; i++)
        #pragma unroll
        for (int j = 0; j < 4; j++)
          acc[i][j] = __builtin_amdgcn_mfma_f32_16x16x32_bf16(a[i][ks], b[j][ks], acc[i][j], 0, 0, 0);
    __builtin_amdgcn_s_setprio(0);
    __builtin_amdgcn_s_barrier();

    #pragma unroll
    for (int i = 0; i < 2; i++) {
      const int R = wm + (i + 2) * 16 + lm;
      #pragma unroll
      for (int ks = 0; ks < 2; ks++)
        a[i][ks] = *reinterpret_cast<const bf16x8*>(
            Abuf + (size_t)R * 64 + (((ks * 4 + lq) ^ (R & 7)) * 8));
    }
    if (pre) { stA(pb, pk, 2); stA(pb, pk, 3); stB(pb, pk, 1); }
    __builtin_amdgcn_s_barrier();
    asm volatile("s_waitcnt lgkmcnt(0)" ::: "memory");
    __builtin_amdgcn_s_setprio(1);
    #pragma unroll
    for (int ks = 0; ks < 2; ks++)
      #pragma unroll
      for (int i = 0; i < 2; i++)
        #pragma unroll
        for (int j = 0; j < 4; j++)
          acc[i + 2][j] = __builtin_amdgcn_mfma_f32_16x16x32_bf16(a[i][ks], b[j][ks], acc[i + 2][j], 0, 0, 0);
    __builtin_amdgcn_s_setprio(0);
    if (t + 1 < NT) {
      if (pre) asm volatile("s_waitcnt vmcnt(6)" ::: "memory");
      else     asm volatile("s_waitcnt vmcnt(0)" ::: "memory");
      __builtin_amdgcn_s_barrier();
    }
    cur = (cur == 2) ? 0 : cur + 1;
  }

  // epilogue: bias (+RoPE for Q/K) + bf16 + scatter into [B,H,S,D]
  const int which = n0 >> 11;   // 0=q 1=k 2=v, uniform per block
  unsigned short* dst = (which == 0) ? Qo : (which == 1) ? Ko : Vo;
  float bv[4];
  #pragma unroll
  for (int j = 0; j < 4; j++) bv[j] = bias[n0 + wn + j * 16 + lm];

  if (which < 2) {
    #pragma unroll
    for (int j = 0; j < 2; j++) {
      const int n = n0 + wn + j * 16 + lm;
      const int e = n & (EMB - 1), h = e >> 6, d = e & 63;   // d < 32
      const float invf = EXP2F((float)d * -0.4152410118609203f);  // 10000^(-d/32)
      #pragma unroll
      for (int i = 0; i < 4; i++) {
        #pragma unroll
        for (int r = 0; r < 4; r++) {
          const int m = m0 + wm + i * 16 + lq * 4 + r;
          const int s = m >> 1, b = m & 1;
          const float v1 = acc[i][j][r]     + bv[j];
          const float v2 = acc[i][j + 2][r] + bv[j + 2];
          float sn, cs;
          __sincosf((float)s * invf, &sn, &cs);
          const size_t base = (((size_t)b * NH + h) * S_LEN + s) * HD + d;
          dst[base]      = f2bf(v1 * cs - v2 * sn);
          dst[base + 32] = f2bf(v2 * cs + v1 * sn);
        }
      }
    }
  } else {
    #pragma unroll
    for (int j = 0; j < 4; j++) {
      const int n = n0 + wn + j * 16 + lm;
      const int e = n & (EMB - 1), h = e >> 6, d = e & 63;
      #pragma unroll
      for (int i = 0; i < 4; i++) {
        #pragma unroll
        for (int r = 0; r < 4; r++) {
          const int m = m0 + wm + i * 16 + lq * 4 + r;
          const int s = m >> 1, b = m & 1;
          dst[(((size_t)b * NH + h) * S_LEN + s) * HD + d] = f2bf(acc[i][j][r] + bv[j]);
        }
      }
    }
  }
}

// ---------------- V [B,H,S,D] -> VT [B,H,D,S] ----------------

__global__ __launch_bounds__(256) void transpose_v(
    const unsigned short* __restrict__ V, unsigned short* __restrict__ VT) {
  __shared__ unsigned short t[64][65];
  const int bh = blockIdx.y;
  const int s0 = blockIdx.x * 64;
  const int tx = threadIdx.x & 63, ty = threadIdx.x >> 6;  // ty 0..3
  const unsigned short* src = V + ((size_t)bh * S_LEN + s0) * HD;
  #pragma unroll
  for (int r = ty; r < 64; r += 4)
    t[r][tx] = src[(size_t)r * HD + tx];
  __syncthreads();
  unsigned short* dst = VT + (size_t)bh * HD * S_LEN + s0;
  #pragma unroll
  for (int r = ty; r < 64; r += 4)
    dst[(size_t)r * S_LEN + tx] = t[tx][r];
}

// ---------------- Flash attention (causal), bf16 MFMA, fixed-max softmax ----------------
// ROUND-5 RESTRUCTURE: 8 waves / 512 threads per block. Waves 0-3 own strip A
// (rows q0A + w4*32), waves 4-7 own strip B. R4's counters showed the binder
// was occupancy/serial-chain (8 waves/CU, MfmaUtil 12%, VALUBusy 28%): one
// wave used to process BOTH strips sequentially (QK -> 32 exp -> P write ->
// lgkm wait -> PV, twice per tile). Now the two strips run CONCURRENTLY in
// different waves; per-wave register state halves; 2 blocks/CU x 8 waves =
// 16 waves/CU (2x R4). V staged in LDS again (R4's V-direct was a regression:
// unprefetched scattered global reads on the critical path).
// P-buffer pad 72 -> 66 shorts: the 4 lq-groups of the P-write land on
// distinct bank quartets (banks 0/4/8/12 apart), removing the 3.2M conflicts.
// LDS: Ks 2x8K | Vs 2x8K | Pbuf 8x32x66 -> 66560 B dynamic, 2 blocks/CU.

constexpr int ATTN_LDS_BYTES = 16384 + 16384 + 8 * 32 * 66 * 2;  // 66560

__global__ __launch_bounds__(512, 2) void attn_kernel(
    const unsigned short* __restrict__ Q,
    const unsigned short* __restrict__ K,
    const unsigned short* __restrict__ VT,
    unsigned short* __restrict__ ctx) {
  extern __shared__ unsigned short lds[];
  char* lds_c = (char*)lds;
  const int bh = blockIdx.x;               // b*32+h
  const int p  = blockIdx.y;               // 0..7 strip pair
  const int tid = threadIdx.x;
  const int wave = tid >> 6, lane = tid & 63;
  const int lm = lane & 15, lq = lane >> 4;
  const int sgrp = wave >> 2;              // 0 = strip A, 1 = strip B
  const int w4 = wave & 3;
  const int b = bh >> 5, h = bh & 31;
  const char* Qb8 = (const char*)(Q  + (size_t)bh * S_LEN * HD);
  const char* Kb8 = (const char*)(K  + (size_t)bh * S_LEN * HD);
  const char* Vb8 = (const char*)(VT + (size_t)bh * HD * S_LEN);

  unsigned short* Pw = lds + 16384 + wave * 32 * 66;   // shorts: Pbuf after Ks+Vs

  const float C = 0.18033688011112042f;    // (1/8) * log2(e)
  const int q0A = p * 128, q0B = (15 - p) * 128;
  const int rr = (sgrp == 0 ? q0A : q0B) + w4 * 32;    // this wave's 32 rows
  const int nt = (q0B >> 6) + 2;           // heavy strip's tile count

  // staging decomposition for 512 threads (dest = base + tid*16, lane-affine):
  // K tile 8 KB: half = tid>>8 (k-cols 0-63B / 64-127B), row = (tid>>2)&63, chunk = tid&3
  // V tile 8 KB: half = tid>>8 (s-cols), d-row = (tid>>2)&63, chunk = tid&3
  const int sthf = tid >> 8, strow = (tid >> 2) & 63, stch = tid & 3;

  // Q fragments (A-layout): rows rr+i*16+lm, k = ks*64+lq*16 bytes
  bf16x8 qf[2][2];                         // [i][ks]
  #pragma unroll
  for (int i = 0; i < 2; i++)
    #pragma unroll
    for (int ks = 0; ks < 2; ks++)
      qf[i][ks] = *reinterpret_cast<const bf16x8*>(
          Qb8 + (size_t)(rr + i*16 + lm) * 128 + ks*64 + lq*16);

  f32x4 O[2][4] = {};
  float l[2][4] = {};

  // stage tile 0 into buf 0
  {
    char* kd = lds_c;            // Ks buf0
    char* vd = lds_c + 16384;    // Vs buf0
    async_copy16(Kb8 + (size_t)strow * 128 + sthf * 64 + stch * 16, kd + tid * 16);
    async_copy16(Vb8 + (size_t)strow * 4096 + sthf * 64 + stch * 16, vd + tid * 16);
  }
  __syncthreads();

  for (int t = 0; t < nt; t++) {
    const int t0 = t * 64;
    const int buf = t & 1;

    if (t + 1 < nt) {
      const int t1 = t0 + 64;
      char* kd = lds_c + (buf ^ 1) * 8192;
      char* vd = lds_c + 16384 + (buf ^ 1) * 8192;
      async_copy16(Kb8 + (size_t)(t1 + strow) * 128 + sthf * 64 + stch * 16, kd + tid * 16);
      async_copy16(Vb8 + (size_t)strow * 4096 + t1 * 2 + sthf * 64 + stch * 16, vd + tid * 16);
    }

    const char* KsB = lds_c + buf * 8192;
    const char* VsB = lds_c + 16384 + buf * 8192;

    if (t0 <= rr + 31) {
      const bool clean = (t0 + 63 <= rr);
      const int jmax  = clean ? 4 : ((rr == t0) ? 2 : 4);
      const int kslim = clean ? 2 : ((rr == t0) ? 1 : 2);
      const int srow_c = rr + lq * 4;

      // S = Q K^T from LDS halves
      f32x4 sc[2][4] = {};
      #pragma unroll
      for (int ks = 0; ks < 2; ks++) {
        bf16x8 kf[4];
        #pragma unroll
        for (int j = 0; j < 4; j++)
          if (j < jmax)
            kf[j] = *reinterpret_cast<const bf16x8*>(
                KsB + ks*4096 + (j*16 + lm)*64 + lq*16);
        #pragma unroll
        for (int i = 0; i < 2; i++)
          #pragma unroll
          for (int j = 0; j < 4; j++)
            if (j < jmax)
              sc[i][j] = __builtin_amdgcn_mfma_f32_16x16x32_bf16(
                  qf[i][ks], kf[j], sc[i][j], 0, 0, 0);
      }

      // exp (fixed max), accumulate per-lane l, write P
      if (clean) {
        #pragma unroll
        for (int i = 0; i < 2; i++)
          #pragma unroll
          for (int j = 0; j < 4; j++)
            #pragma unroll
            for (int r = 0; r < 4; r++) {
              const float pe = EXP2F(sc[i][j][r] * C);
              l[i][r] += pe;
              Pw[(i*16 + lq*4 + r) * 66 + j*16 + lm] = f2bf(pe);
            }
      } else {
        #pragma unroll
        for (int i = 0; i < 2; i++)
          #pragma unroll
          for (int j = 0; j < 4; j++)
            if (j < jmax)
              #pragma unroll
              for (int r = 0; r < 4; r++) {
                const int srow = srow_c + i*16 + r;
                const int tcol = t0 + j*16 + lm;
                const float pe = (tcol <= srow) ? EXP2F(sc[i][j][r] * C) : 0.0f;
                l[i][r] += pe;
                Pw[(i*16 + lq*4 + r) * 66 + j*16 + lm] = f2bf(pe);
              }
      }

      // O += P V
      #pragma unroll
      for (int ks = 0; ks < 2; ks++) {
        if (ks < kslim) {
          bf16x8 pf[2], vf[4];
          #pragma unroll
          for (int i = 0; i < 2; i++)
            pf[i] = *reinterpret_cast<const bf16x8*>(Pw + (i*16 + lm)*66 + ks*32 + lq*8);
          #pragma unroll
          for (int j = 0; j < 4; j++)
            vf[j] = *reinterpret_cast<const bf16x8*>(
                VsB + ks*4096 + (j*16 + lm)*64 + lq*16);
          #pragma unroll
          for (int i = 0; i < 2; i++)
            #pragma unroll
            for (int j = 0; j < 4; j++)
              O[i][j] = __builtin_amdgcn_mfma_f32_16x16x32_bf16(
                  pf[i], vf[j], O[i][j], 0, 0, 0);
        }
      }
    }
    __syncthreads();   // compute(t) done; stage(t+1) drained (vmcnt 0 via syncthreads)
  }

  // epilogue: reduce l across 16-lane column groups, scale, store ctx [S,B,E]
  #pragma unroll
  for (int i = 0; i < 2; i++) {
    #pragma unroll
    for (int r = 0; r < 4; r++) {
      float sum = l[i][r];
      sum += __shfl_xor(sum, 1, 64);
      sum += __shfl_xor(sum, 2, 64);
      sum += __shfl_xor(sum, 4, 64);
      sum += __shfl_xor(sum, 8, 64);
      const float inv = 1.0f / sum;
      const int srow = rr + lq*4 + i*16 + r;
      #pragma unroll
      for (int j = 0; j < 4; j++) {
        const int d = j*16 + lm;
        ctx[((size_t)srow * BATCH + b) * EMB + h*HD + d] = f2bf(O[i][j][r] * inv);
      }
    }
  }
}

// ---------------- Output GEMM: same R1 256x128 schedule, f32 + bias epilogue ----------------

__global__ __launch_bounds__(512, 2) void gemm_out(
    const unsigned short* __restrict__ A,
    const unsigned short* __restrict__ Wt,
    const float* __restrict__ bias,
    float* __restrict__ out) {
  extern __shared__ unsigned short lds[];
  const int tid = threadIdx.x;
  const int n0 = blockIdx.x * 128;
  const int m0 = blockIdx.y * 256;
  const int wave = tid >> 6, lane = tid & 63;
  const int wm = (wave >> 1) * 64, wn = (wave & 1) * 64;
  const int lm = lane & 15, lq = lane >> 4;
  const int K = 2048;
  const int NT = K / 64;

  const int srow = tid >> 3;
  const int gch  = (tid & 7) ^ (srow & 7);
  const unsigned short* Ab = A  + (size_t)(m0 + srow) * K + gch * 8;
  const unsigned short* Bb = Wt + (size_t)(n0 + srow) * K + gch * 8;

  auto stA = [&](int bufi, int k0, int rep) {
    async_copy16(Ab + (size_t)rep * 64 * K + k0,
                 lds + (size_t)bufi * TILE_SH + ((size_t)rep * 512 + tid) * 8);
  };
  auto stB = [&](int bufi, int k0, int rep) {
    async_copy16(Bb + (size_t)rep * 64 * K + k0,
                 lds + (size_t)bufi * TILE_SH + 16384 + ((size_t)rep * 512 + tid) * 8);
  };

  f32x4 acc[4][4] = {};

  stA(0, 0, 0); stA(0, 0, 1); stA(0, 0, 2); stA(0, 0, 3); stB(0, 0, 0); stB(0, 0, 1);
  stA(1, 64, 0); stA(1, 64, 1); stA(1, 64, 2); stA(1, 64, 3); stB(1, 64, 0); stB(1, 64, 1);
  asm volatile("s_waitcnt vmcnt(6)" ::: "memory");
  __builtin_amdgcn_s_barrier();

  int cur = 0;
  for (int t = 0; t < NT; t++) {
    const unsigned short* Abuf = lds + (size_t)cur * TILE_SH;
    const unsigned short* Bbuf = Abuf + 16384;
    const int pb = (cur >= 1) ? cur - 1 : 2;
    const int pk = (t + 2) * 64;
    const bool pre = (t + 2) < NT;

    bf16x8 b[4][2], a[2][2];
    #pragma unroll
    for (int j = 0; j < 4; j++) {
      const int R = wn + j * 16 + lm;
      #pragma unroll
      for (int ks = 0; ks < 2; ks++)
        b[j][ks] = *reinterpret_cast<const bf16x8*>(
            Bbuf + (size_t)R * 64 + (((ks * 4 + lq) ^ (R & 7)) * 8));
    }
    #pragma unroll
    for (int i = 0; i < 2; i++) {
      const int R = wm + i * 16 + lm;
      #pragma unroll
      for (int ks = 0; ks < 2; ks++)
        a[i][ks] = *reinterpret_cast<const bf16x8*>(
            Abuf + (size_t)R * 64 + (((ks * 4 + lq) ^ (R & 7)) * 8));
    }
    if (pre) { stA(pb, pk, 0); stA(pb, pk, 1); stB(pb, pk, 0); }
    __builtin_amdgcn_s_barrier();
    asm volatile("s_waitcnt lgkmcnt(0)" ::: "memory");
    __builtin_amdgcn_s_setprio(1);
    #pragma unroll
    for (int ks = 0; ks < 2; ks++)
      #pragma unroll
      for (int i = 0; i < 2; i++)
        #pragma unroll
        for (int j = 0; j < 4; j++)
          acc[i][j] = __builtin_amdgcn_mfma_f32_16x16x32_bf16(a[i][ks], b[j][ks], acc[i][j], 0, 0, 0);
    __builtin_amdgcn_s_setprio(0);
    __builtin_amdgcn_s_barrier();

    #pragma unroll
    for (int i = 0; i < 2; i++) {
      const int R = wm + (i + 2) * 16 + lm;
      #pragma unroll
      for (int ks = 0; ks < 2; ks++)
        a[i][ks] = *reinterpret_cast<const bf16x8*>(
            Abuf + (size_t)R * 64 + (((ks * 4 + lq) ^ (R & 7)) * 8));
    }
    if (pre) { stA(pb, pk, 2); stA(pb, pk, 3); stB(pb, pk, 1); }
    __builtin_amdgcn_s_barrier();
    asm volatile("s_waitcnt lgkmcnt(0)" ::: "memory");
    __builtin_amdgcn_s_setprio(1);
    #pragma unroll
    for (int ks = 0; ks < 2; ks++)
      #pragma unroll
      for (int i = 0; i < 2; i++)
        #pragma unroll
        for (int j = 0; j < 4; j++)
          acc[i + 2][j] = __builtin_amdgcn_mfma_f32_16x16x32_bf16(a[i][ks], b[j][ks], acc[i + 2][j], 0, 0, 0);
    __builtin_amdgcn_s_setprio(0);
    if (t + 1 < NT) {
      if (pre) asm volatile("s_waitcnt vmcnt(6)" ::: "memory");
      else     asm volatile("s_waitcnt vmcnt(0)" ::: "memory");
      __builtin_amdgcn_s_barrier();
    }
    cur = (cur == 2) ? 0 : cur + 1;
  }

  #pragma unroll
  for (int j = 0; j < 4; j++) {
    const int n = n0 + wn + j * 16 + lm;
    const float bv = bias[n];
    #pragma unroll
    for (int i = 0; i < 4; i++) {
      #pragma unroll
      for (int r = 0; r < 4; r++) {
        const int m = m0 + wm + i * 16 + lq * 4 + r;
        out[(size_t)m * EMB + n] = acc[i][j][r] + bv;
      }
    }
  }
}

// ---------------- host launcher ----------------

extern "C" void kernel_launch(void* const* d_in, const int* in_sizes, int n_in,
                              void* d_out, int out_size, void* d_ws, size_t ws_size,
                              hipStream_t stream) {
  const float* hidden = (const float*)d_in[0];
  const float* qkv_w  = (const float*)d_in[1];
  const float* qkv_b  = (const float*)d_in[2];
  const float* out_w  = (const float*)d_in[3];
  const float* out_b  = (const float*)d_in[4];
  float* out = (float*)d_out;

  static bool attr_set = false;
  if (!attr_set) {
    hipFuncSetAttribute(reinterpret_cast<const void*>(gemm_qkv),
                        hipFuncAttributeMaxDynamicSharedMemorySize, GEMM_LDS_BYTES);
    hipFuncSetAttribute(reinterpret_cast<const void*>(gemm_out),
                        hipFuncAttributeMaxDynamicSharedMemorySize, GEMM_LDS_BYTES);
    hipFuncSetAttribute(reinterpret_cast<const void*>(attn_kernel),
                        hipFuncAttributeMaxDynamicSharedMemorySize, ATTN_LDS_BYTES);
    attr_set = true;
  }

  unsigned short* ws = (unsigned short*)d_ws;
  unsigned short* hbf   = ws;                                  // 4096*2048
  unsigned short* qkvwT = hbf   + (size_t)M_ROWS * EMB;        // 6144*2048
  unsigned short* outwT = qkvwT + (size_t)QKV_N * EMB;         // 2048*2048
  unsigned short* Qb    = outwT + (size_t)EMB * EMB;           // 64*2048*64 each
  unsigned short* Kb    = Qb    + (size_t)64 * S_LEN * HD;
  unsigned short* Vb    = Kb    + (size_t)64 * S_LEN * HD;
  unsigned short* VTb   = Vb    + (size_t)64 * S_LEN * HD;
  unsigned short* ctx   = VTb   + (size_t)64 * S_LEN * HD;     // 4096*2048

  // 1. casts / transposes
  cast_to_bf16<<<(M_ROWS * EMB / 4) / 256, 256, 0, stream>>>(hidden, hbf, M_ROWS * EMB / 4);
  transpose_cast<<<dim3(QKV_N / 64, EMB / 64), 256, 0, stream>>>(qkv_w, qkvwT, EMB, QKV_N);
  transpose_cast<<<dim3(EMB / 64, EMB / 64), 256, 0, stream>>>(out_w, outwT, EMB, EMB);

  // 2. fused QKV projection + bias + RoPE + scatter (R1-best 256x128 schedule)
  gemm_qkv<<<dim3(QKV_N / 128, M_ROWS / 256), 512, GEMM_LDS_BYTES, stream>>>(
      hbf, qkvwT, qkv_b, Qb, Kb, Vb);

  // 3. V transpose
  transpose_v<<<dim3(S_LEN / 64, 64), 256, 0, stream>>>(Vb, VTb);

  // 4. causal flash attention (8 waves/block: strip A = waves 0-3, strip B = waves 4-7)
  attn_kernel<<<dim3(64, 8), 512, ATTN_LDS_BYTES, stream>>>(Qb, Kb, VTb, ctx);

  // 5. output projection (R1 256x128 schedule)
  gemm_out<<<dim3(EMB / 128, M_ROWS / 256), 512, GEMM_LDS_BYTES, stream>>>(
      ctx, outwT, out_b, out);
}

// Round 6
// 375.539 us; speedup vs baseline: 1.0648x; 1.0407x over previous
//
#include <hip/hip_runtime.h>
#include <hip/hip_bf16.h>

// Problem constants (S=2048, B=2, E=2048, H=32, D=64)
#define S_LEN 2048
#define BATCH 2
#define EMB   2048
#define NH    32
#define HD    64
#define M_ROWS (S_LEN * BATCH)   // 4096
#define QKV_N  (3 * EMB)         // 6144

typedef short bf16x8 __attribute__((ext_vector_type(8)));
typedef float f32x4  __attribute__((ext_vector_type(4)));

__device__ __forceinline__ unsigned short f2bf(float f) {
  unsigned int u = __float_as_uint(f);
  u += 0x7fffu + ((u >> 16) & 1u);       // round-to-nearest-even
  return (unsigned short)(u >> 16);
}
__device__ __forceinline__ float bf2f(unsigned short h) {
  return __uint_as_float(((unsigned int)h) << 16);
}
__device__ __forceinline__ void async_copy16(const void* g, void* lds_d) {
  __builtin_amdgcn_global_load_lds(
      (const __attribute__((address_space(1))) void*)g,
      (__attribute__((address_space(3))) void*)lds_d, 16, 0, 0);
}

#if __has_builtin(__builtin_amdgcn_exp2f)
#define EXP2F(x) __builtin_amdgcn_exp2f(x)
#else
#define EXP2F(x) __expf((x) * 0.6931471805599453f)
#endif

// ---------------- prep kernels ----------------

__global__ __launch_bounds__(256) void cast_to_bf16(
    const float* __restrict__ in, unsigned short* __restrict__ out, int n4) {
  int i = blockIdx.x * 256 + threadIdx.x;
  if (i >= n4) return;
  float4 v = reinterpret_cast<const float4*>(in)[i];
  ushort4 o;
  o.x = f2bf(v.x); o.y = f2bf(v.y); o.z = f2bf(v.z); o.w = f2bf(v.w);
  reinterpret_cast<ushort4*>(out)[i] = o;
}

// in [R][C] f32 -> out [C][R] bf16.  64x64 tile, both sides coalesced.
__global__ __launch_bounds__(256) void transpose_cast(
    const float* __restrict__ in, unsigned short* __restrict__ out, int R, int C) {
  __shared__ unsigned short t[64][65];
  const int bc = blockIdx.x * 64, br = blockIdx.y * 64;
  const int tx = threadIdx.x & 63, ty = threadIdx.x >> 6;   // ty 0..3
  #pragma unroll
  for (int rr = ty; rr < 64; rr += 4)
    t[rr][tx] = f2bf(in[(size_t)(br + rr) * C + bc + tx]);
  __syncthreads();
  #pragma unroll
  for (int rr = ty; rr < 64; rr += 4)
    out[(size_t)(bc + rr) * R + br + tx] = t[tx][rr];
}

// ---------------- QKV GEMM (R1-measured-best): 256x128 tile, BK=64, 8 waves,
// triple-buffered LDS, 2 phases/K-tile with counted vmcnt + setprio.

constexpr int TILE_SH = 24576;                 // shorts/buffer: A 256x64 + B 128x64
constexpr int GEMM_LDS_BYTES = 3 * TILE_SH * 2; // 147456 B

__global__ __launch_bounds__(512, 2) void gemm_qkv(
    const unsigned short* __restrict__ A,
    const unsigned short* __restrict__ Wt,
    const float* __restrict__ bias,
    unsigned short* __restrict__ Qo,
    unsigned short* __restrict__ Ko,
    unsigned short* __restrict__ Vo) {
  extern __shared__ unsigned short lds[];
  const int tid = threadIdx.x;               // 0..511
  const int n0 = blockIdx.x * 128;
  const int m0 = blockIdx.y * 256;
  const int wave = tid >> 6, lane = tid & 63;
  const int wm = (wave >> 1) * 64, wn = (wave & 1) * 64;   // 4M x 2N waves
  const int lm = lane & 15, lq = lane >> 4;
  const int K = 2048;
  const int NT = K / 64;                     // 32 K-tiles

  const int srow = tid >> 3;                 // 0..63
  const int gch  = (tid & 7) ^ (srow & 7);
  const unsigned short* Ab = A  + (size_t)(m0 + srow) * K + gch * 8;
  const unsigned short* Bb = Wt + (size_t)(n0 + srow) * K + gch * 8;

  auto stA = [&](int bufi, int k0, int rep) {
    async_copy16(Ab + (size_t)rep * 64 * K + k0,
                 lds + (size_t)bufi * TILE_SH + ((size_t)rep * 512 + tid) * 8);
  };
  auto stB = [&](int bufi, int k0, int rep) {
    async_copy16(Bb + (size_t)rep * 64 * K + k0,
                 lds + (size_t)bufi * TILE_SH + 16384 + ((size_t)rep * 512 + tid) * 8);
  };

  f32x4 acc[4][4] = {};

  stA(0, 0, 0); stA(0, 0, 1); stA(0, 0, 2); stA(0, 0, 3); stB(0, 0, 0); stB(0, 0, 1);
  stA(1, 64, 0); stA(1, 64, 1); stA(1, 64, 2); stA(1, 64, 3); stB(1, 64, 0); stB(1, 64, 1);
  asm volatile("s_waitcnt vmcnt(6)" ::: "memory");
  __builtin_amdgcn_s_barrier();

  int cur = 0;
  for (int t = 0; t < NT; t++) {
    const unsigned short* Abuf = lds + (size_t)cur * TILE_SH;
    const unsigned short* Bbuf = Abuf + 16384;
    const int pb = (cur >= 1) ? cur - 1 : 2;   // (cur+2)%3
    const int pk = (t + 2) * 64;
    const bool pre = (t + 2) < NT;

    bf16x8 b[4][2], a[2][2];
    #pragma unroll
    for (int j = 0; j < 4; j++) {
      const int R = wn + j * 16 + lm;
      #pragma unroll
      for (int ks = 0; ks < 2; ks++)
        b[j][ks] = *reinterpret_cast<const bf16x8*>(
            Bbuf + (size_t)R * 64 + (((ks * 4 + lq) ^ (R & 7)) * 8));
    }
    #pragma unroll
    for (int i = 0; i < 2; i++) {
      const int R = wm + i * 16 + lm;
      #pragma unroll
      for (int ks = 0; ks < 2; ks++)
        a[i][ks] = *reinterpret_cast<const bf16x8*>(
            Abuf + (size_t)R * 64 + (((ks * 4 + lq) ^ (R & 7)) * 8));
    }
    if (pre) { stA(pb, pk, 0); stA(pb, pk, 1); stB(pb, pk, 0); }
    __builtin_amdgcn_s_barrier();
    asm volatile("s_waitcnt lgkmcnt(0)" ::: "memory");
    __builtin_amdgcn_s_setprio(1);
    #pragma unroll
    for (int ks = 0; ks < 2; ks++)
      #pragma unroll
      for (int i = 0; i < 2; i++)
        #pragma unroll
        for (int j = 0; j < 4; j++)
          acc[i][j] = __builtin_amdgcn_mfma_f32_16x16x32_bf16(a[i][ks], b[j][ks], acc[i][j], 0, 0, 0);
    __builtin_amdgcn_s_setprio(0);
    __builtin_amdgcn_s_barrier();

    #pragma unroll
    for (int i = 0; i < 2; i++) {
      const int R = wm + (i + 2) * 16 + lm;
      #pragma unroll
      for (int ks = 0; ks < 2; ks++)
        a[i][ks] = *reinterpret_cast<const bf16x8*>(
            Abuf + (size_t)R * 64 + (((ks * 4 + lq) ^ (R & 7)) * 8));
    }
    if (pre) { stA(pb, pk, 2); stA(pb, pk, 3); stB(pb, pk, 1); }
    __builtin_amdgcn_s_barrier();
    asm volatile("s_waitcnt lgkmcnt(0)" ::: "memory");
    __builtin_amdgcn_s_setprio(1);
    #pragma unroll
    for (int ks = 0; ks < 2; ks++)
      #pragma unroll
      for (int i = 0; i < 2; i++)
        #pragma unroll
        for (int j = 0; j < 4; j++)
          acc[i + 2][j] = __builtin_amdgcn_mfma_f32_16x16x32_bf16(a[i][ks], b[j][ks], acc[i + 2][j], 0, 0, 0);
    __builtin_amdgcn_s_setprio(0);
    if (t + 1 < NT) {
      if (pre) asm volatile("s_waitcnt vmcnt(6)" ::: "memory");
      else     asm volatile("s_waitcnt vmcnt(0)" ::: "memory");
      __builtin_amdgcn_s_barrier();
    }
    cur = (cur == 2) ? 0 : cur + 1;
  }

  // epilogue: bias (+RoPE for Q/K) + bf16 + scatter into [B,H,S,D]
  const int which = n0 >> 11;   // 0=q 1=k 2=v, uniform per block
  unsigned short* dst = (which == 0) ? Qo : (which == 1) ? Ko : Vo;
  float bv[4];
  #pragma unroll
  for (int j = 0; j < 4; j++) bv[j] = bias[n0 + wn + j * 16 + lm];

  if (which < 2) {
    #pragma unroll
    for (int j = 0; j < 2; j++) {
      const int n = n0 + wn + j * 16 + lm;
      const int e = n & (EMB - 1), h = e >> 6, d = e & 63;   // d < 32
      const float invf = EXP2F((float)d * -0.4152410118609203f);  // 10000^(-d/32)
      #pragma unroll
      for (int i = 0; i < 4; i++) {
        #pragma unroll
        for (int r = 0; r < 4; r++) {
          const int m = m0 + wm + i * 16 + lq * 4 + r;
          const int s = m >> 1, b = m & 1;
          const float v1 = acc[i][j][r]     + bv[j];
          const float v2 = acc[i][j + 2][r] + bv[j + 2];
          float sn, cs;
          __sincosf((float)s * invf, &sn, &cs);
          const size_t base = (((size_t)b * NH + h) * S_LEN + s) * HD + d;
          dst[base]      = f2bf(v1 * cs - v2 * sn);
          dst[base + 32] = f2bf(v2 * cs + v1 * sn);
        }
      }
    }
  } else {
    #pragma unroll
    for (int j = 0; j < 4; j++) {
      const int n = n0 + wn + j * 16 + lm;
      const int e = n & (EMB - 1), h = e >> 6, d = e & 63;
      #pragma unroll
      for (int i = 0; i < 4; i++) {
        #pragma unroll
        for (int r = 0; r < 4; r++) {
          const int m = m0 + wm + i * 16 + lq * 4 + r;
          const int s = m >> 1, b = m & 1;
          dst[(((size_t)b * NH + h) * S_LEN + s) * HD + d] = f2bf(acc[i][j][r] + bv[j]);
        }
      }
    }
  }
}

// ---------------- V [B,H,S,D] -> VT [B,H,D,S] ----------------

__global__ __launch_bounds__(256) void transpose_v(
    const unsigned short* __restrict__ V, unsigned short* __restrict__ VT) {
  __shared__ unsigned short t[64][65];
  const int bh = blockIdx.y;
  const int s0 = blockIdx.x * 64;
  const int tx = threadIdx.x & 63, ty = threadIdx.x >> 6;  // ty 0..3
  const unsigned short* src = V + ((size_t)bh * S_LEN + s0) * HD;
  #pragma unroll
  for (int r = ty; r < 64; r += 4)
    t[r][tx] = src[(size_t)r * HD + tx];
  __syncthreads();
  unsigned short* dst = VT + (size_t)bh * HD * S_LEN + s0;
  #pragma unroll
  for (int r = ty; r < 64; r += 4)
    dst[(size_t)r * S_LEN + tx] = t[tx][r];
}

// ---------------- Flash attention (causal), bf16 MFMA, fixed-max softmax ----------------
// ROUND-6: reverted to the R0-VERIFIED merged-strip structure (4 waves x 2
// sequential strips; R5's strip-split halved wave utilization since strips are
// causally asymmetric). ONE change vs R0: the P buffer's pad-72 layout had a
// 4-way bank conflict on every scalar P-write (row stride 144 B -> lq{0,2} and
// lq{1,3} octets collide; R4 measured 3.2M conflicts). New layout: stride 64
// shorts (no pad) with 8-short-chunk XOR swizzle phys_cc = cc ^ (((row>>2)&3)<<1).
//  - writes (row=i*16+lq*4+r -> key=lq<<1): lq octets land on disjoint 8-bank
//    ranges, 2 lanes/bank = free;
//  - b128 reads (row=i*16+lm -> key=(lm>>2)<<1): 8 lanes per 16B granule =
//    balanced minimum; chunks stay 16B-aligned.
// Key depends on row only -> write/read consistent. K/V LDS reads were already
// balanced (verified by bank algebra) and stay unchanged.

__global__ __launch_bounds__(256) void attn_kernel(
    const unsigned short* __restrict__ Q,
    const unsigned short* __restrict__ K,
    const unsigned short* __restrict__ VT,
    unsigned short* __restrict__ ctx) {
  const int bh = blockIdx.x;               // b*32+h
  const int p  = blockIdx.y;               // 0..7 strip pair
  const int tid = threadIdx.x;
  const int wave = tid >> 6, lane = tid & 63;
  const int lm = lane & 15, lq = lane >> 4;
  const int b = bh >> 5, h = bh & 31;
  const char* Qb8 = (const char*)(Q  + (size_t)bh * S_LEN * HD);
  const char* Kb8 = (const char*)(K  + (size_t)bh * S_LEN * HD);
  const char* Vb8 = (const char*)(VT + (size_t)bh * HD * S_LEN);

  __shared__ __align__(16) unsigned short Ks[2][2][64][32];  // [buf][half][row][32]
  __shared__ __align__(16) unsigned short Vs[2][2][64][32];
  __shared__ __align__(16) unsigned short Pbuf[4][32][64];   // swizzled, no pad
  unsigned short* Pw = &Pbuf[wave][0][0];

  const float C = 0.18033688011112042f;    // (1/8) * log2(e)
  const int q0A = p * 128, q0B = (15 - p) * 128;
  const int r0A = q0A + wave * 32, r0B = q0B + wave * 32;
  const int nt = (q0B >> 6) + 2;           // heavy strip's tile count

  const int srw = tid >> 2, sc16 = (tid & 3) * 16;

  bf16x8 qf[2][2][2];                      // [strip][i][ks]
  #pragma unroll
  for (int s = 0; s < 2; s++) {
    const int rr = (s == 0) ? r0A : r0B;
    #pragma unroll
    for (int i = 0; i < 2; i++)
      #pragma unroll
      for (int ks = 0; ks < 2; ks++)
        qf[s][i][ks] = *reinterpret_cast<const bf16x8*>(
            Qb8 + (size_t)(rr + i*16 + lm) * 128 + ks*64 + lq*16);
  }

  f32x4 O[2][2][4] = {};
  float l[2][2][4] = {};

  {
    char* kd = (char*)&Ks[0][0][0][0];
    char* vd = (char*)&Vs[0][0][0][0];
    async_copy16(Kb8 + (size_t)srw * 128      + sc16, kd        + tid*16);
    async_copy16(Kb8 + (size_t)srw * 128 + 64 + sc16, kd + 4096 + tid*16);
    async_copy16(Vb8 + (size_t)srw * 4096      + sc16, vd        + tid*16);
    async_copy16(Vb8 + (size_t)srw * 4096 + 64 + sc16, vd + 4096 + tid*16);
  }
  __syncthreads();

  for (int t = 0; t < nt; t++) {
    const int t0 = t * 64;
    const int buf = t & 1;

    if (t + 1 < nt) {
      const int t1 = t0 + 64;
      char* kd = (char*)&Ks[buf ^ 1][0][0][0];
      char* vd = (char*)&Vs[buf ^ 1][0][0][0];
      async_copy16(Kb8 + (size_t)(t1 + srw) * 128      + sc16, kd        + tid*16);
      async_copy16(Kb8 + (size_t)(t1 + srw) * 128 + 64 + sc16, kd + 4096 + tid*16);
      async_copy16(Vb8 + (size_t)srw * 4096 + t1*2      + sc16, vd        + tid*16);
      async_copy16(Vb8 + (size_t)srw * 4096 + t1*2 + 64 + sc16, vd + 4096 + tid*16);
    }

    const char* KsB = (const char*)&Ks[buf][0][0][0];
    const char* VsB = (const char*)&Vs[buf][0][0][0];

    #pragma unroll
    for (int s = 0; s < 2; s++) {
      const int rr = (s == 0) ? r0A : r0B;
      if (t0 <= rr + 31) {
        const bool clean = (t0 + 63 <= rr);
        const int jmax  = clean ? 4 : ((rr == t0) ? 2 : 4);
        const int kslim = clean ? 2 : ((rr == t0) ? 1 : 2);
        const int srow_c = rr + lq * 4;

        f32x4 sc[2][4] = {};
        #pragma unroll
        for (int ks = 0; ks < 2; ks++) {
          bf16x8 kf[4];
          #pragma unroll
          for (int j = 0; j < 4; j++)
            if (j < jmax)
              kf[j] = *reinterpret_cast<const bf16x8*>(
                  KsB + ks*4096 + (j*16 + lm)*64 + lq*16);
          #pragma unroll
          for (int i = 0; i < 2; i++)
            #pragma unroll
            for (int j = 0; j < 4; j++)
              if (j < jmax)
                sc[i][j] = __builtin_amdgcn_mfma_f32_16x16x32_bf16(
                    qf[s][i][ks], kf[j], sc[i][j], 0, 0, 0);
        }

        // exp (fixed max), accumulate per-lane l, write P (swizzled chunks)
        if (clean) {
          #pragma unroll
          for (int i = 0; i < 2; i++)
            #pragma unroll
            for (int j = 0; j < 4; j++) {
              const int pcol = (((2*j + (lm >> 3)) ^ (lq << 1)) << 3) + (lm & 7);
              #pragma unroll
              for (int r = 0; r < 4; r++) {
                const float pe = EXP2F(sc[i][j][r] * C);
                l[s][i][r] += pe;
                Pw[(i*16 + lq*4 + r) * 64 + pcol] = f2bf(pe);
              }
            }
        } else {
          #pragma unroll
          for (int i = 0; i < 2; i++)
            #pragma unroll
            for (int j = 0; j < 4; j++)
              if (j < jmax) {
                const int pcol = (((2*j + (lm >> 3)) ^ (lq << 1)) << 3) + (lm & 7);
                #pragma unroll
                for (int r = 0; r < 4; r++) {
                  const int srow = srow_c + i*16 + r;
                  const int tcol = t0 + j*16 + lm;
                  const float pe = (tcol <= srow) ? EXP2F(sc[i][j][r] * C) : 0.0f;
                  l[s][i][r] += pe;
                  Pw[(i*16 + lq*4 + r) * 64 + pcol] = f2bf(pe);
                }
              }
        }

        // O += P V
        #pragma unroll
        for (int ks = 0; ks < 2; ks++) {
          if (ks < kslim) {
            bf16x8 pf[2], vf[4];
            #pragma unroll
            for (int i = 0; i < 2; i++)
              pf[i] = *reinterpret_cast<const bf16x8*>(
                  Pw + (i*16 + lm)*64 + (((ks*4 + lq) ^ ((lm >> 2) << 1)) << 3));
            #pragma unroll
            for (int j = 0; j < 4; j++)
              vf[j] = *reinterpret_cast<const bf16x8*>(
                  VsB + ks*4096 + (j*16 + lm)*64 + lq*16);
            #pragma unroll
            for (int i = 0; i < 2; i++)
              #pragma unroll
              for (int j = 0; j < 4; j++)
                O[s][i][j] = __builtin_amdgcn_mfma_f32_16x16x32_bf16(
                    pf[i], vf[j], O[s][i][j], 0, 0, 0);
          }
        }
      }
    }
    __syncthreads();
  }

  #pragma unroll
  for (int s = 0; s < 2; s++) {
    const int rr = (s == 0) ? r0A : r0B;
    #pragma unroll
    for (int i = 0; i < 2; i++) {
      #pragma unroll
      for (int r = 0; r < 4; r++) {
        float sum = l[s][i][r];
        sum += __shfl_xor(sum, 1, 64);
        sum += __shfl_xor(sum, 2, 64);
        sum += __shfl_xor(sum, 4, 64);
        sum += __shfl_xor(sum, 8, 64);
        const float inv = 1.0f / sum;
        const int srow = rr + lq*4 + i*16 + r;
        #pragma unroll
        for (int j = 0; j < 4; j++) {
          const int d = j*16 + lm;
          ctx[((size_t)srow * BATCH + b) * EMB + h*HD + d] = f2bf(O[s][i][j][r] * inv);
        }
      }
    }
  }
}

// ---------------- Output GEMM: same R1 256x128 schedule, f32 + bias epilogue ----------------

__global__ __launch_bounds__(512, 2) void gemm_out(
    const unsigned short* __restrict__ A,
    const unsigned short* __restrict__ Wt,
    const float* __restrict__ bias,
    float* __restrict__ out) {
  extern __shared__ unsigned short lds[];
  const int tid = threadIdx.x;
  const int n0 = blockIdx.x * 128;
  const int m0 = blockIdx.y * 256;
  const int wave = tid >> 6, lane = tid & 63;
  const int wm = (wave >> 1) * 64, wn = (wave & 1) * 64;
  const int lm = lane & 15, lq = lane >> 4;
  const int K = 2048;
  const int NT = K / 64;

  const int srow = tid >> 3;
  const int gch  = (tid & 7) ^ (srow & 7);
  const unsigned short* Ab = A  + (size_t)(m0 + srow) * K + gch * 8;
  const unsigned short* Bb = Wt + (size_t)(n0 + srow) * K + gch * 8;

  auto stA = [&](int bufi, int k0, int rep) {
    async_copy16(Ab + (size_t)rep * 64 * K + k0,
                 lds + (size_t)bufi * TILE_SH + ((size_t)rep * 512 + tid) * 8);
  };
  auto stB = [&](int bufi, int k0, int rep) {
    async_copy16(Bb + (size_t)rep * 64 * K + k0,
                 lds + (size_t)bufi * TILE_SH + 16384 + ((size_t)rep * 512 + tid) * 8);
  };

  f32x4 acc[4][4] = {};

  stA(0, 0, 0); stA(0, 0, 1); stA(0, 0, 2); stA(0, 0, 3); stB(0, 0, 0); stB(0, 0, 1);
  stA(1, 64, 0); stA(1, 64, 1); stA(1, 64, 2); stA(1, 64, 3); stB(1, 64, 0); stB(1, 64, 1);
  asm volatile("s_waitcnt vmcnt(6)" ::: "memory");
  __builtin_amdgcn_s_barrier();

  int cur = 0;
  for (int t = 0; t < NT; t++) {
    const unsigned short* Abuf = lds + (size_t)cur * TILE_SH;
    const unsigned short* Bbuf = Abuf + 16384;
    const int pb = (cur >= 1) ? cur - 1 : 2;
    const int pk = (t + 2) * 64;
    const bool pre = (t + 2) < NT;

    bf16x8 b[4][2], a[2][2];
    #pragma unroll
    for (int j = 0; j < 4; j++) {
      const int R = wn + j * 16 + lm;
      #pragma unroll
      for (int ks = 0; ks < 2; ks++)
        b[j][ks] = *reinterpret_cast<const bf16x8*>(
            Bbuf + (size_t)R * 64 + (((ks * 4 + lq) ^ (R & 7)) * 8));
    }
    #pragma unroll
    for (int i = 0; i < 2; i++) {
      const int R = wm + i * 16 + lm;
      #pragma unroll
      for (int ks = 0; ks < 2; ks++)
        a[i][ks] = *reinterpret_cast<const bf16x8*>(
            Abuf + (size_t)R * 64 + (((ks * 4 + lq) ^ (R & 7)) * 8));
    }
    if (pre) { stA(pb, pk, 0); stA(pb, pk, 1); stB(pb, pk, 0); }
    __builtin_amdgcn_s_barrier();
    asm volatile("s_waitcnt lgkmcnt(0)" ::: "memory");
    __builtin_amdgcn_s_setprio(1);
    #pragma unroll
    for (int ks = 0; ks < 2; ks++)
      #pragma unroll
      for (int i = 0; i < 2; i++)
        #pragma unroll
        for (int j = 0; j < 4; j++)
          acc[i][j] = __builtin_amdgcn_mfma_f32_16x16x32_bf16(a[i][ks], b[j][ks], acc[i][j], 0, 0, 0);
    __builtin_amdgcn_s_setprio(0);
    __builtin_amdgcn_s_barrier();

    #pragma unroll
    for (int i = 0; i < 2; i++) {
      const int R = wm + (i + 2) * 16 + lm;
      #pragma unroll
      for (int ks = 0; ks < 2; ks++)
        a[i][ks] = *reinterpret_cast<const bf16x8*>(
            Abuf + (size_t)R * 64 + (((ks * 4 + lq) ^ (R & 7)) * 8));
    }
    if (pre) { stA(pb, pk, 2); stA(pb, pk, 3); stB(pb, pk, 1); }
    __builtin_amdgcn_s_barrier();
    asm volatile("s_waitcnt lgkmcnt(0)" ::: "memory");
    __builtin_amdgcn_s_setprio(1);
    #pragma unroll
    for (int ks = 0; ks < 2; ks++)
      #pragma unroll
      for (int i = 0; i < 2; i++)
        #pragma unroll
        for (int j = 0; j < 4; j++)
          acc[i + 2][j] = __builtin_amdgcn_mfma_f32_16x16x32_bf16(a[i][ks], b[j][ks], acc[i + 2][j], 0, 0, 0);
    __builtin_amdgcn_s_setprio(0);
    if (t + 1 < NT) {
      if (pre) asm volatile("s_waitcnt vmcnt(6)" ::: "memory");
      else     asm volatile("s_waitcnt vmcnt(0)" ::: "memory");
      __builtin_amdgcn_s_barrier();
    }
    cur = (cur == 2) ? 0 : cur + 1;
  }

  #pragma unroll
  for (int j = 0; j < 4; j++) {
    const int n = n0 + wn + j * 16 + lm;
    const float bv = bias[n];
    #pragma unroll
    for (int i = 0; i < 4; i++) {
      #pragma unroll
      for (int r = 0; r < 4; r++) {
        const int m = m0 + wm + i * 16 + lq * 4 + r;
        out[(size_t)m * EMB + n] = acc[i][j][r] + bv;
      }
    }
  }
}

// ---------------- host launcher ----------------

extern "C" void kernel_launch(void* const* d_in, const int* in_sizes, int n_in,
                              void* d_out, int out_size, void* d_ws, size_t ws_size,
                              hipStream_t stream) {
  const float* hidden = (const float*)d_in[0];
  const float* qkv_w  = (const float*)d_in[1];
  const float* qkv_b  = (const float*)d_in[2];
  const float* out_w  = (const float*)d_in[3];
  const float* out_b  = (const float*)d_in[4];
  float* out = (float*)d_out;

  static bool attr_set = false;
  if (!attr_set) {
    hipFuncSetAttribute(reinterpret_cast<const void*>(gemm_qkv),
                        hipFuncAttributeMaxDynamicSharedMemorySize, GEMM_LDS_BYTES);
    hipFuncSetAttribute(reinterpret_cast<const void*>(gemm_out),
                        hipFuncAttributeMaxDynamicSharedMemorySize, GEMM_LDS_BYTES);
    attr_set = true;
  }

  unsigned short* ws = (unsigned short*)d_ws;
  unsigned short* hbf   = ws;                                  // 4096*2048
  unsigned short* qkvwT = hbf   + (size_t)M_ROWS * EMB;        // 6144*2048
  unsigned short* outwT = qkvwT + (size_t)QKV_N * EMB;         // 2048*2048
  unsigned short* Qb    = outwT + (size_t)EMB * EMB;           // 64*2048*64 each
  unsigned short* Kb    = Qb    + (size_t)64 * S_LEN * HD;
  unsigned short* Vb    = Kb    + (size_t)64 * S_LEN * HD;
  unsigned short* VTb   = Vb    + (size_t)64 * S_LEN * HD;
  unsigned short* ctx   = VTb   + (size_t)64 * S_LEN * HD;     // 4096*2048

  // 1. casts / transposes
  cast_to_bf16<<<(M_ROWS * EMB / 4) / 256, 256, 0, stream>>>(hidden, hbf, M_ROWS * EMB / 4);
  transpose_cast<<<dim3(QKV_N / 64, EMB / 64), 256, 0, stream>>>(qkv_w, qkvwT, EMB, QKV_N);
  transpose_cast<<<dim3(EMB / 64, EMB / 64), 256, 0, stream>>>(out_w, outwT, EMB, EMB);

  // 2. fused QKV projection + bias + RoPE + scatter (R1-best 256x128 schedule)
  gemm_qkv<<<dim3(QKV_N / 128, M_ROWS / 256), 512, GEMM_LDS_BYTES, stream>>>(
      hbf, qkvwT, qkv_b, Qb, Kb, Vb);

  // 3. V transpose
  transpose_v<<<dim3(S_LEN / 64, 64), 256, 0, stream>>>(Vb, VTb);

  // 4. causal flash attention (R0 merged-strip structure + swizzled P buffer)
  attn_kernel<<<dim3(64, 8), 256, 0, stream>>>(Qb, Kb, VTb, ctx);

  // 5. output projection (R1 256x128 schedule)
  gemm_out<<<dim3(EMB / 128, M_ROWS / 256), 512, GEMM_LDS_BYTES, stream>>>(
      ctx, outwT, out_b, out);
}

// Round 7
// 361.079 us; speedup vs baseline: 1.1074x; 1.0400x over previous
//
#include <hip/hip_runtime.h>
#include <hip/hip_bf16.h>

// Problem constants (S=2048, B=2, E=2048, H=32, D=64)
#define S_LEN 2048
#define BATCH 2
#define EMB   2048
#define NH    32
#define HD    64
#define M_ROWS (S_LEN * BATCH)   // 4096
#define QKV_N  (3 * EMB)         // 6144

typedef short bf16x8 __attribute__((ext_vector_type(8)));
typedef float f32x4  __attribute__((ext_vector_type(4)));

__device__ __forceinline__ unsigned short f2bf(float f) {
  unsigned int u = __float_as_uint(f);
  u += 0x7fffu + ((u >> 16) & 1u);       // round-to-nearest-even
  return (unsigned short)(u >> 16);
}
__device__ __forceinline__ float bf2f(unsigned short h) {
  return __uint_as_float(((unsigned int)h) << 16);
}
__device__ __forceinline__ void async_copy16(const void* g, void* lds_d) {
  __builtin_amdgcn_global_load_lds(
      (const __attribute__((address_space(1))) void*)g,
      (__attribute__((address_space(3))) void*)lds_d, 16, 0, 0);
}

#if __has_builtin(__builtin_amdgcn_exp2f)
#define EXP2F(x) __builtin_amdgcn_exp2f(x)
#else
#define EXP2F(x) __expf((x) * 0.6931471805599453f)
#endif

// ---------------- prep: ONE launch for cast + both weight transposes ----------------
// R7: the totals ledger shows ~100 us of inter-launch gaps over 7 launches;
// merging the 3 independent prep kernels into one flat-grid launch removes 2.
// Bodies are byte-identical to the previously verified kernels.

#define CAST_BLKS  (M_ROWS * EMB / 4 / 256)          // 8192
#define TCQ_BX     (QKV_N / 64)                      // 96
#define TCQ_BLKS   (TCQ_BX * (EMB / 64))             // 3072
#define TCO_BX     (EMB / 64)                        // 32
#define TCO_BLKS   (TCO_BX * (EMB / 64))             // 1024
#define PREP_BLKS  (CAST_BLKS + TCQ_BLKS + TCO_BLKS) // 12288

__device__ __forceinline__ void transpose_body(
    const float* __restrict__ in, unsigned short* __restrict__ out,
    int R, int C, int bx, int by, int tid) {
  __shared__ unsigned short t[64][65];
  const int bc = bx * 64, br = by * 64;
  const int tx = tid & 63, ty = tid >> 6;   // ty 0..3
  #pragma unroll
  for (int rr = ty; rr < 64; rr += 4)
    t[rr][tx] = f2bf(in[(size_t)(br + rr) * C + bc + tx]);
  __syncthreads();
  #pragma unroll
  for (int rr = ty; rr < 64; rr += 4)
    out[(size_t)(bc + rr) * R + br + tx] = t[tx][rr];
}

__global__ __launch_bounds__(256) void prep_all(
    const float* __restrict__ hidden, unsigned short* __restrict__ hbf,
    const float* __restrict__ qkv_w, unsigned short* __restrict__ qkvwT,
    const float* __restrict__ out_w, unsigned short* __restrict__ outwT) {
  const int bid = blockIdx.x, tid = threadIdx.x;
  if (bid < CAST_BLKS) {
    const int i = bid * 256 + tid;
    float4 v = reinterpret_cast<const float4*>(hidden)[i];
    ushort4 o;
    o.x = f2bf(v.x); o.y = f2bf(v.y); o.z = f2bf(v.z); o.w = f2bf(v.w);
    reinterpret_cast<ushort4*>(hbf)[i] = o;
  } else if (bid < CAST_BLKS + TCQ_BLKS) {
    const int b = bid - CAST_BLKS;
    transpose_body(qkv_w, qkvwT, EMB, QKV_N, b % TCQ_BX, b / TCQ_BX, tid);
  } else {
    const int b = bid - CAST_BLKS - TCQ_BLKS;
    transpose_body(out_w, outwT, EMB, EMB, b % TCO_BX, b / TCO_BX, tid);
  }
}

// ---------------- QKV GEMM (R1-measured-best): 256x128 tile, BK=64, 8 waves,
// triple-buffered LDS, 2 phases/K-tile with counted vmcnt + setprio.
// R7: the V-block (which==2) epilogue now writes VT[b,h,d,s] DIRECTLY via an
// LDS transpose (tile [128 n][264] shorts, 16B-aligned rows, bank-verified
// free writes / balanced reads) -> transpose_v kernel and the Vb buffer are
// eliminated (one launch + 48 MB HBM traffic saved).

constexpr int TILE_SH = 24576;                 // shorts/buffer: A 256x64 + B 128x64
constexpr int GEMM_LDS_BYTES = 3 * TILE_SH * 2; // 147456 B

__global__ __launch_bounds__(512, 2) void gemm_qkv(
    const unsigned short* __restrict__ A,
    const unsigned short* __restrict__ Wt,
    const float* __restrict__ bias,
    unsigned short* __restrict__ Qo,
    unsigned short* __restrict__ Ko,
    unsigned short* __restrict__ VTo) {
  extern __shared__ unsigned short lds[];
  const int tid = threadIdx.x;               // 0..511
  const int n0 = blockIdx.x * 128;
  const int m0 = blockIdx.y * 256;
  const int wave = tid >> 6, lane = tid & 63;
  const int wm = (wave >> 1) * 64, wn = (wave & 1) * 64;   // 4M x 2N waves
  const int lm = lane & 15, lq = lane >> 4;
  const int K = 2048;
  const int NT = K / 64;                     // 32 K-tiles

  const int srow = tid >> 3;                 // 0..63
  const int gch  = (tid & 7) ^ (srow & 7);
  const unsigned short* Ab = A  + (size_t)(m0 + srow) * K + gch * 8;
  const unsigned short* Bb = Wt + (size_t)(n0 + srow) * K + gch * 8;

  auto stA = [&](int bufi, int k0, int rep) {
    async_copy16(Ab + (size_t)rep * 64 * K + k0,
                 lds + (size_t)bufi * TILE_SH + ((size_t)rep * 512 + tid) * 8);
  };
  auto stB = [&](int bufi, int k0, int rep) {
    async_copy16(Bb + (size_t)rep * 64 * K + k0,
                 lds + (size_t)bufi * TILE_SH + 16384 + ((size_t)rep * 512 + tid) * 8);
  };

  f32x4 acc[4][4] = {};

  stA(0, 0, 0); stA(0, 0, 1); stA(0, 0, 2); stA(0, 0, 3); stB(0, 0, 0); stB(0, 0, 1);
  stA(1, 64, 0); stA(1, 64, 1); stA(1, 64, 2); stA(1, 64, 3); stB(1, 64, 0); stB(1, 64, 1);
  asm volatile("s_waitcnt vmcnt(6)" ::: "memory");
  __builtin_amdgcn_s_barrier();

  int cur = 0;
  for (int t = 0; t < NT; t++) {
    const unsigned short* Abuf = lds + (size_t)cur * TILE_SH;
    const unsigned short* Bbuf = Abuf + 16384;
    const int pb = (cur >= 1) ? cur - 1 : 2;   // (cur+2)%3
    const int pk = (t + 2) * 64;
    const bool pre = (t + 2) < NT;

    bf16x8 b[4][2], a[2][2];
    #pragma unroll
    for (int j = 0; j < 4; j++) {
      const int R = wn + j * 16 + lm;
      #pragma unroll
      for (int ks = 0; ks < 2; ks++)
        b[j][ks] = *reinterpret_cast<const bf16x8*>(
            Bbuf + (size_t)R * 64 + (((ks * 4 + lq) ^ (R & 7)) * 8));
    }
    #pragma unroll
    for (int i = 0; i < 2; i++) {
      const int R = wm + i * 16 + lm;
      #pragma unroll
      for (int ks = 0; ks < 2; ks++)
        a[i][ks] = *reinterpret_cast<const bf16x8*>(
            Abuf + (size_t)R * 64 + (((ks * 4 + lq) ^ (R & 7)) * 8));
    }
    if (pre) { stA(pb, pk, 0); stA(pb, pk, 1); stB(pb, pk, 0); }
    __builtin_amdgcn_s_barrier();
    asm volatile("s_waitcnt lgkmcnt(0)" ::: "memory");
    __builtin_amdgcn_s_setprio(1);
    #pragma unroll
    for (int ks = 0; ks < 2; ks++)
      #pragma unroll
      for (int i = 0; i < 2; i++)
        #pragma unroll
        for (int j = 0; j < 4; j++)
          acc[i][j] = __builtin_amdgcn_mfma_f32_16x16x32_bf16(a[i][ks], b[j][ks], acc[i][j], 0, 0, 0);
    __builtin_amdgcn_s_setprio(0);
    __builtin_amdgcn_s_barrier();

    #pragma unroll
    for (int i = 0; i < 2; i++) {
      const int R = wm + (i + 2) * 16 + lm;
      #pragma unroll
      for (int ks = 0; ks < 2; ks++)
        a[i][ks] = *reinterpret_cast<const bf16x8*>(
            Abuf + (size_t)R * 64 + (((ks * 4 + lq) ^ (R & 7)) * 8));
    }
    if (pre) { stA(pb, pk, 2); stA(pb, pk, 3); stB(pb, pk, 1); }
    __builtin_amdgcn_s_barrier();
    asm volatile("s_waitcnt lgkmcnt(0)" ::: "memory");
    __builtin_amdgcn_s_setprio(1);
    #pragma unroll
    for (int ks = 0; ks < 2; ks++)
      #pragma unroll
      for (int i = 0; i < 2; i++)
        #pragma unroll
        for (int j = 0; j < 4; j++)
          acc[i + 2][j] = __builtin_amdgcn_mfma_f32_16x16x32_bf16(a[i][ks], b[j][ks], acc[i + 2][j], 0, 0, 0);
    __builtin_amdgcn_s_setprio(0);
    if (t + 1 < NT) {
      if (pre) asm volatile("s_waitcnt vmcnt(6)" ::: "memory");
      else     asm volatile("s_waitcnt vmcnt(0)" ::: "memory");
      __builtin_amdgcn_s_barrier();
    }
    cur = (cur == 2) ? 0 : cur + 1;
  }

  // epilogue
  const int which = n0 >> 11;   // 0=q 1=k 2=v, uniform per block
  float bv[4];
  #pragma unroll
  for (int j = 0; j < 4; j++) bv[j] = bias[n0 + wn + j * 16 + lm];

  if (which < 2) {
    unsigned short* dst = (which == 0) ? Qo : Ko;
    // RoPE pairs (d, d+32) = (acc[i][j], acc[i][j+2]) for j=0,1 (d = j*16+lm)
    #pragma unroll
    for (int j = 0; j < 2; j++) {
      const int n = n0 + wn + j * 16 + lm;
      const int e = n & (EMB - 1), h = e >> 6, d = e & 63;   // d < 32
      const float invf = EXP2F((float)d * -0.4152410118609203f);  // 10000^(-d/32)
      #pragma unroll
      for (int i = 0; i < 4; i++) {
        #pragma unroll
        for (int r = 0; r < 4; r++) {
          const int m = m0 + wm + i * 16 + lq * 4 + r;
          const int s = m >> 1, b = m & 1;
          const float v1 = acc[i][j][r]     + bv[j];
          const float v2 = acc[i][j + 2][r] + bv[j + 2];
          float sn, cs;
          __sincosf((float)s * invf, &sn, &cs);
          const size_t base = (((size_t)b * NH + h) * S_LEN + s) * HD + d;
          dst[base]      = f2bf(v1 * cs - v2 * sn);
          dst[base + 32] = f2bf(v2 * cs + v1 * sn);
        }
      }
    }
  } else {
    // V: route tile through LDS -> write VT[b,h,d,s] with coalesced s-major stores.
    // LDS tile T[128 nl][264]: nl = local n (h,d), inner = b*128 + s_local (+8 pad).
    // Row stride 264 shorts = 528 B (16B-aligned). Writes: banks 4*(lm&7)+lq ->
    // conflict-free; b128 reads: 8 lanes per 16B granule -> balanced.
    __syncthreads();                       // K-loop LDS now dead everywhere
    unsigned short* T = lds;
    #pragma unroll
    for (int j = 0; j < 4; j++) {
      const int nl = wn + j * 16 + lm;
      #pragma unroll
      for (int i = 0; i < 4; i++) {
        const int sbase = (wm >> 1) + i * 8 + lq * 2;   // s_local of r=0/1
        #pragma unroll
        for (int r = 0; r < 4; r++)
          T[nl * 264 + (r & 1) * 128 + sbase + (r >> 1)] = f2bf(acc[i][j][r] + bv[j]);
      }
    }
    __syncthreads();
    const int h0 = (n0 & (EMB - 1)) >> 6;  // first head of this block's 128 cols
    const int s0 = m0 >> 1;                // block's s base (128 rows per b)
    #pragma unroll
    for (int k = 0; k < 8; k++) {
      const int c = k * 512 + tid;         // 4096 16B-chunks: [256 rows][16 chunks]
      const int row = c >> 4, ch = c & 15;
      const int nl = row >> 1, bb = row & 1;
      const bf16x8 v = *reinterpret_cast<const bf16x8*>(T + nl * 264 + bb * 128 + ch * 8);
      const int hh = h0 + (nl >> 6), d = nl & 63;
      *reinterpret_cast<bf16x8*>(
          VTo + (((size_t)bb * NH + hh) * HD + d) * S_LEN + s0 + ch * 8) = v;
    }
  }
}

// ---------------- Flash attention (causal), bf16 MFMA, fixed-max softmax ----------------
// EXACT R0-verified structure (merged strip pair, double-buffered K/V in LDS,
// pad-72 P buffer, 1 barrier/tile). R6's P-swizzle variant measured ~9 us
// SLOWER (extra per-write XOR VALU in a VALU-busy loop outweighed the 3.2M
// bank-conflict cost) -> reverted.

__global__ __launch_bounds__(256) void attn_kernel(
    const unsigned short* __restrict__ Q,
    const unsigned short* __restrict__ K,
    const unsigned short* __restrict__ VT,
    unsigned short* __restrict__ ctx) {
  const int bh = blockIdx.x;               // b*32+h
  const int p  = blockIdx.y;               // 0..7 strip pair
  const int tid = threadIdx.x;
  const int wave = tid >> 6, lane = tid & 63;
  const int lm = lane & 15, lq = lane >> 4;
  const int b = bh >> 5, h = bh & 31;
  const char* Qb8 = (const char*)(Q  + (size_t)bh * S_LEN * HD);
  const char* Kb8 = (const char*)(K  + (size_t)bh * S_LEN * HD);
  const char* Vb8 = (const char*)(VT + (size_t)bh * HD * S_LEN);

  __shared__ __align__(16) unsigned short Ks[2][2][64][32];  // [buf][half][row][32]
  __shared__ __align__(16) unsigned short Vs[2][2][64][32];
  __shared__ __align__(16) unsigned short Pbuf[4][32][72];
  unsigned short* Pw = &Pbuf[wave][0][0];

  const float C = 0.18033688011112042f;    // (1/8) * log2(e)
  const int q0A = p * 128, q0B = (15 - p) * 128;
  const int r0A = q0A + wave * 32, r0B = q0B + wave * 32;
  const int nt = (q0B >> 6) + 2;           // heavy strip's tile count

  const int srw = tid >> 2, sc16 = (tid & 3) * 16;

  bf16x8 qf[2][2][2];                      // [strip][i][ks]
  #pragma unroll
  for (int s = 0; s < 2; s++) {
    const int rr = (s == 0) ? r0A : r0B;
    #pragma unroll
    for (int i = 0; i < 2; i++)
      #pragma unroll
      for (int ks = 0; ks < 2; ks++)
        qf[s][i][ks] = *reinterpret_cast<const bf16x8*>(
            Qb8 + (size_t)(rr + i*16 + lm) * 128 + ks*64 + lq*16);
  }

  f32x4 O[2][2][4] = {};
  float l[2][2][4] = {};

  {
    char* kd = (char*)&Ks[0][0][0][0];
    char* vd = (char*)&Vs[0][0][0][0];
    async_copy16(Kb8 + (size_t)srw * 128      + sc16, kd        + tid*16);
    async_copy16(Kb8 + (size_t)srw * 128 + 64 + sc16, kd + 4096 + tid*16);
    async_copy16(Vb8 + (size_t)srw * 4096      + sc16, vd        + tid*16);
    async_copy16(Vb8 + (size_t)srw * 4096 + 64 + sc16, vd + 4096 + tid*16);
  }
  __syncthreads();

  for (int t = 0; t < nt; t++) {
    const int t0 = t * 64;
    const int buf = t & 1;

    if (t + 1 < nt) {
      const int t1 = t0 + 64;
      char* kd = (char*)&Ks[buf ^ 1][0][0][0];
      char* vd = (char*)&Vs[buf ^ 1][0][0][0];
      async_copy16(Kb8 + (size_t)(t1 + srw) * 128      + sc16, kd        + tid*16);
      async_copy16(Kb8 + (size_t)(t1 + srw) * 128 + 64 + sc16, kd + 4096 + tid*16);
      async_copy16(Vb8 + (size_t)srw * 4096 + t1*2      + sc16, vd        + tid*16);
      async_copy16(Vb8 + (size_t)srw * 4096 + t1*2 + 64 + sc16, vd + 4096 + tid*16);
    }

    const char* KsB = (const char*)&Ks[buf][0][0][0];
    const char* VsB = (const char*)&Vs[buf][0][0][0];

    #pragma unroll
    for (int s = 0; s < 2; s++) {
      const int rr = (s == 0) ? r0A : r0B;
      if (t0 <= rr + 31) {
        const bool clean = (t0 + 63 <= rr);
        const int jmax  = clean ? 4 : ((rr == t0) ? 2 : 4);
        const int kslim = clean ? 2 : ((rr == t0) ? 1 : 2);
        const int srow_c = rr + lq * 4;

        f32x4 sc[2][4] = {};
        #pragma unroll
        for (int ks = 0; ks < 2; ks++) {
          bf16x8 kf[4];
          #pragma unroll
          for (int j = 0; j < 4; j++)
            if (j < jmax)
              kf[j] = *reinterpret_cast<const bf16x8*>(
                  KsB + ks*4096 + (j*16 + lm)*64 + lq*16);
          #pragma unroll
          for (int i = 0; i < 2; i++)
            #pragma unroll
            for (int j = 0; j < 4; j++)
              if (j < jmax)
                sc[i][j] = __builtin_amdgcn_mfma_f32_16x16x32_bf16(
                    qf[s][i][ks], kf[j], sc[i][j], 0, 0, 0);
        }

        if (clean) {
          #pragma unroll
          for (int i = 0; i < 2; i++)
            #pragma unroll
            for (int j = 0; j < 4; j++)
              #pragma unroll
              for (int r = 0; r < 4; r++) {
                const float pe = EXP2F(sc[i][j][r] * C);
                l[s][i][r] += pe;
                Pw[(i*16 + lq*4 + r) * 72 + j*16 + lm] = f2bf(pe);
              }
        } else {
          #pragma unroll
          for (int i = 0; i < 2; i++)
            #pragma unroll
            for (int j = 0; j < 4; j++)
              if (j < jmax)
                #pragma unroll
                for (int r = 0; r < 4; r++) {
                  const int srow = srow_c + i*16 + r;
                  const int tcol = t0 + j*16 + lm;
                  const float pe = (tcol <= srow) ? EXP2F(sc[i][j][r] * C) : 0.0f;
                  l[s][i][r] += pe;
                  Pw[(i*16 + lq*4 + r) * 72 + j*16 + lm] = f2bf(pe);
                }
        }

        #pragma unroll
        for (int ks = 0; ks < 2; ks++) {
          if (ks < kslim) {
            bf16x8 pf[2], vf[4];
            #pragma unroll
            for (int i = 0; i < 2; i++)
              pf[i] = *reinterpret_cast<const bf16x8*>(Pw + (i*16 + lm)*72 + ks*32 + lq*8);
            #pragma unroll
            for (int j = 0; j < 4; j++)
              vf[j] = *reinterpret_cast<const bf16x8*>(
                  VsB + ks*4096 + (j*16 + lm)*64 + lq*16);
            #pragma unroll
            for (int i = 0; i < 2; i++)
              #pragma unroll
              for (int j = 0; j < 4; j++)
                O[s][i][j] = __builtin_amdgcn_mfma_f32_16x16x32_bf16(
                    pf[i], vf[j], O[s][i][j], 0, 0, 0);
          }
        }
      }
    }
    __syncthreads();
  }

  #pragma unroll
  for (int s = 0; s < 2; s++) {
    const int rr = (s == 0) ? r0A : r0B;
    #pragma unroll
    for (int i = 0; i < 2; i++) {
      #pragma unroll
      for (int r = 0; r < 4; r++) {
        float sum = l[s][i][r];
        sum += __shfl_xor(sum, 1, 64);
        sum += __shfl_xor(sum, 2, 64);
        sum += __shfl_xor(sum, 4, 64);
        sum += __shfl_xor(sum, 8, 64);
        const float inv = 1.0f / sum;
        const int srow = rr + lq*4 + i*16 + r;
        #pragma unroll
        for (int j = 0; j < 4; j++) {
          const int d = j*16 + lm;
          ctx[((size_t)srow * BATCH + b) * EMB + h*HD + d] = f2bf(O[s][i][j][r] * inv);
        }
      }
    }
  }
}

// ---------------- Output GEMM: R1 256x128 schedule, f32 + bias epilogue ----------------

__global__ __launch_bounds__(512, 2) void gemm_out(
    const unsigned short* __restrict__ A,
    const unsigned short* __restrict__ Wt,
    const float* __restrict__ bias,
    float* __restrict__ out) {
  extern __shared__ unsigned short lds[];
  const int tid = threadIdx.x;
  const int n0 = blockIdx.x * 128;
  const int m0 = blockIdx.y * 256;
  const int wave = tid >> 6, lane = tid & 63;
  const int wm = (wave >> 1) * 64, wn = (wave & 1) * 64;
  const int lm = lane & 15, lq = lane >> 4;
  const int K = 2048;
  const int NT = K / 64;

  const int srow = tid >> 3;
  const int gch  = (tid & 7) ^ (srow & 7);
  const unsigned short* Ab = A  + (size_t)(m0 + srow) * K + gch * 8;
  const unsigned short* Bb = Wt + (size_t)(n0 + srow) * K + gch * 8;

  auto stA = [&](int bufi, int k0, int rep) {
    async_copy16(Ab + (size_t)rep * 64 * K + k0,
                 lds + (size_t)bufi * TILE_SH + ((size_t)rep * 512 + tid) * 8);
  };
  auto stB = [&](int bufi, int k0, int rep) {
    async_copy16(Bb + (size_t)rep * 64 * K + k0,
                 lds + (size_t)bufi * TILE_SH + 16384 + ((size_t)rep * 512 + tid) * 8);
  };

  f32x4 acc[4][4] = {};

  stA(0, 0, 0); stA(0, 0, 1); stA(0, 0, 2); stA(0, 0, 3); stB(0, 0, 0); stB(0, 0, 1);
  stA(1, 64, 0); stA(1, 64, 1); stA(1, 64, 2); stA(1, 64, 3); stB(1, 64, 0); stB(1, 64, 1);
  asm volatile("s_waitcnt vmcnt(6)" ::: "memory");
  __builtin_amdgcn_s_barrier();

  int cur = 0;
  for (int t = 0; t < NT; t++) {
    const unsigned short* Abuf = lds + (size_t)cur * TILE_SH;
    const unsigned short* Bbuf = Abuf + 16384;
    const int pb = (cur >= 1) ? cur - 1 : 2;
    const int pk = (t + 2) * 64;
    const bool pre = (t + 2) < NT;

    bf16x8 b[4][2], a[2][2];
    #pragma unroll
    for (int j = 0; j < 4; j++) {
      const int R = wn + j * 16 + lm;
      #pragma unroll
      for (int ks = 0; ks < 2; ks++)
        b[j][ks] = *reinterpret_cast<const bf16x8*>(
            Bbuf + (size_t)R * 64 + (((ks * 4 + lq) ^ (R & 7)) * 8));
    }
    #pragma unroll
    for (int i = 0; i < 2; i++) {
      const int R = wm + i * 16 + lm;
      #pragma unroll
      for (int ks = 0; ks < 2; ks++)
        a[i][ks] = *reinterpret_cast<const bf16x8*>(
            Abuf + (size_t)R * 64 + (((ks * 4 + lq) ^ (R & 7)) * 8));
    }
    if (pre) { stA(pb, pk, 0); stA(pb, pk, 1); stB(pb, pk, 0); }
    __builtin_amdgcn_s_barrier();
    asm volatile("s_waitcnt lgkmcnt(0)" ::: "memory");
    __builtin_amdgcn_s_setprio(1);
    #pragma unroll
    for (int ks = 0; ks < 2; ks++)
      #pragma unroll
      for (int i = 0; i < 2; i++)
        #pragma unroll
        for (int j = 0; j < 4; j++)
          acc[i][j] = __builtin_amdgcn_mfma_f32_16x16x32_bf16(a[i][ks], b[j][ks], acc[i][j], 0, 0, 0);
    __builtin_amdgcn_s_setprio(0);
    __builtin_amdgcn_s_barrier();

    #pragma unroll
    for (int i = 0; i < 2; i++) {
      const int R = wm + (i + 2) * 16 + lm;
      #pragma unroll
      for (int ks = 0; ks < 2; ks++)
        a[i][ks] = *reinterpret_cast<const bf16x8*>(
            Abuf + (size_t)R * 64 + (((ks * 4 + lq) ^ (R & 7)) * 8));
    }
    if (pre) { stA(pb, pk, 2); stA(pb, pk, 3); stB(pb, pk, 1); }
    __builtin_amdgcn_s_barrier();
    asm volatile("s_waitcnt lgkmcnt(0)" ::: "memory");
    __builtin_amdgcn_s_setprio(1);
    #pragma unroll
    for (int ks = 0; ks < 2; ks++)
      #pragma unroll
      for (int i = 0; i < 2; i++)
        #pragma unroll
        for (int j = 0; j < 4; j++)
          acc[i + 2][j] = __builtin_amdgcn_mfma_f32_16x16x32_bf16(a[i][ks], b[j][ks], acc[i + 2][j], 0, 0, 0);
    __builtin_amdgcn_s_setprio(0);
    if (t + 1 < NT) {
      if (pre) asm volatile("s_waitcnt vmcnt(6)" ::: "memory");
      else     asm volatile("s_waitcnt vmcnt(0)" ::: "memory");
      __builtin_amdgcn_s_barrier();
    }
    cur = (cur == 2) ? 0 : cur + 1;
  }

  #pragma unroll
  for (int j = 0; j < 4; j++) {
    const int n = n0 + wn + j * 16 + lm;
    const float bv = bias[n];
    #pragma unroll
    for (int i = 0; i < 4; i++) {
      #pragma unroll
      for (int r = 0; r < 4; r++) {
        const int m = m0 + wm + i * 16 + lq * 4 + r;
        out[(size_t)m * EMB + n] = acc[i][j][r] + bv;
      }
    }
  }
}

// ---------------- host launcher ----------------

extern "C" void kernel_launch(void* const* d_in, const int* in_sizes, int n_in,
                              void* d_out, int out_size, void* d_ws, size_t ws_size,
                              hipStream_t stream) {
  const float* hidden = (const float*)d_in[0];
  const float* qkv_w  = (const float*)d_in[1];
  const float* qkv_b  = (const float*)d_in[2];
  const float* out_w  = (const float*)d_in[3];
  const float* out_b  = (const float*)d_in[4];
  float* out = (float*)d_out;

  static bool attr_set = false;
  if (!attr_set) {
    hipFuncSetAttribute(reinterpret_cast<const void*>(gemm_qkv),
                        hipFuncAttributeMaxDynamicSharedMemorySize, GEMM_LDS_BYTES);
    hipFuncSetAttribute(reinterpret_cast<const void*>(gemm_out),
                        hipFuncAttributeMaxDynamicSharedMemorySize, GEMM_LDS_BYTES);
    attr_set = true;
  }

  unsigned short* ws = (unsigned short*)d_ws;
  unsigned short* hbf   = ws;                                  // 4096*2048
  unsigned short* qkvwT = hbf   + (size_t)M_ROWS * EMB;        // 6144*2048
  unsigned short* outwT = qkvwT + (size_t)QKV_N * EMB;         // 2048*2048
  unsigned short* Qb    = outwT + (size_t)EMB * EMB;           // 64*2048*64 each
  unsigned short* Kb    = Qb    + (size_t)64 * S_LEN * HD;
  unsigned short* VTb   = Kb    + (size_t)64 * S_LEN * HD;
  unsigned short* ctx   = VTb   + (size_t)64 * S_LEN * HD;     // 4096*2048

  // 1. single prep launch: cast + both weight transposes
  prep_all<<<PREP_BLKS, 256, 0, stream>>>(hidden, hbf, qkv_w, qkvwT, out_w, outwT);

  // 2. fused QKV projection + bias + RoPE + scatter; V written directly as VT
  gemm_qkv<<<dim3(QKV_N / 128, M_ROWS / 256), 512, GEMM_LDS_BYTES, stream>>>(
      hbf, qkvwT, qkv_b, Qb, Kb, VTb);

  // 3. causal flash attention (R0-exact merged-strip structure)
  attn_kernel<<<dim3(64, 8), 256, 0, stream>>>(Qb, Kb, VTb, ctx);

  // 4. output projection
  gemm_out<<<dim3(EMB / 128, M_ROWS / 256), 512, GEMM_LDS_BYTES, stream>>>(
      ctx, outwT, out_b, out);
}